// Round 3
// baseline (119755.774 us; speedup 1.0000x reference)
//
#include <hip/hip_runtime.h>

// SimplePerformer forward, fp32, per-batch end-to-end pipeline (~92 MB ws).
// B=8 G=20000 D=256 H=8 DH=32 L=4 M=128 FF=1024
#define Bb 8
#define Gg 20000
#define Dd 256
#define Hh 8
#define DHh 32
#define Ll 4
#define Mm 128
#define FFf 1024
#define CHK 2500   // row chunk for FF/proj/head GEMMs (8 chunks per batch)

__device__ __forceinline__ float geluf(float x) {
    return 0.5f * x * (1.0f + erff(x * 0.70710678118654752f));
}

// ---------------------------------------------------------------- GEMM 128x128
// C = act(A@Bw + bias) [+ res] [+ C_old]; A [Mrows x K] row-major.
// grid = (N/128, ceil(Mrows/128)), block 256. N,K multiples of 128/16.
__global__ __launch_bounds__(256) void gemm128(
    const float* __restrict__ A, const float* __restrict__ Bw,
    const float* __restrict__ bias, const float* __restrict__ res,
    float* __restrict__ C, int Mrows, int N, int K, int act, int addC)
{
    __shared__ float As[16][132];
    __shared__ float Bs[16][132];
    const int t  = threadIdx.x;
    const int tx = t & 15, ty = t >> 4;
    const int row0 = blockIdx.y * 128;
    const int col0 = blockIdx.x * 128;

    const int lar = t >> 2;          // 0..63
    const int laq = (t & 3) * 4;     // 0,4,8,12
    const int ra0 = min(row0 + lar, Mrows - 1);
    const int ra1 = min(row0 + lar + 64, Mrows - 1);
    const float* pA0 = A + (size_t)ra0 * K + laq;
    const float* pA1 = A + (size_t)ra1 * K + laq;
    const int lbr = t >> 4;          // 0..15
    const int lbc = (t & 15) * 4;
    const float* pB = Bw + (size_t)lbr * N + col0 + lbc;

    float acc[8][8];
#pragma unroll
    for (int i = 0; i < 8; i++)
#pragma unroll
        for (int j = 0; j < 8; j++) acc[i][j] = 0.f;

    for (int k0 = 0; k0 < K; k0 += 16) {
        float4 a0 = *(const float4*)pA0;
        float4 a1 = *(const float4*)pA1;
        float4 b0 = *(const float4*)pB;
        float4 b1 = *(const float4*)(pB + 64);
        __syncthreads();
        As[laq+0][lar] = a0.x; As[laq+1][lar] = a0.y;
        As[laq+2][lar] = a0.z; As[laq+3][lar] = a0.w;
        As[laq+0][lar+64] = a1.x; As[laq+1][lar+64] = a1.y;
        As[laq+2][lar+64] = a1.z; As[laq+3][lar+64] = a1.w;
        *(float4*)&Bs[lbr][lbc]      = b0;
        *(float4*)&Bs[lbr][lbc + 64] = b1;
        __syncthreads();
#pragma unroll
        for (int kk = 0; kk < 16; kk++) {
            float4 xa0 = *(const float4*)&As[kk][ty*4];
            float4 xa1 = *(const float4*)&As[kk][64 + ty*4];
            float4 xb0 = *(const float4*)&Bs[kk][tx*4];
            float4 xb1 = *(const float4*)&Bs[kk][64 + tx*4];
            float av[8] = {xa0.x,xa0.y,xa0.z,xa0.w, xa1.x,xa1.y,xa1.z,xa1.w};
            float bv[8] = {xb0.x,xb0.y,xb0.z,xb0.w, xb1.x,xb1.y,xb1.z,xb1.w};
#pragma unroll
            for (int i = 0; i < 8; i++)
#pragma unroll
                for (int j = 0; j < 8; j++) acc[i][j] += av[i]*bv[j];
        }
        pA0 += 16; pA1 += 16; pB += (size_t)16 * N;
    }

#pragma unroll
    for (int i = 0; i < 8; i++) {
        int row = row0 + ((i < 4) ? (ty*4 + i) : (64 + ty*4 + i - 4));
        if (row >= Mrows) continue;
#pragma unroll
        for (int hf = 0; hf < 2; hf++) {
            int col = col0 + hf*64 + tx*4;
            float v[4];
#pragma unroll
            for (int j = 0; j < 4; j++) v[j] = acc[i][hf*4 + j];
            if (bias) {
#pragma unroll
                for (int j = 0; j < 4; j++) v[j] += bias[col + j];
            }
            if (act == 1) {
#pragma unroll
                for (int j = 0; j < 4; j++) v[j] = fmaxf(v[j], 0.f);
            } else if (act == 2) {
#pragma unroll
                for (int j = 0; j < 4; j++) v[j] = geluf(v[j]);
            }
            size_t cidx = (size_t)row * N + col;
            if (res) {
                float4 r4 = *(const float4*)&res[cidx];
                v[0] += r4.x; v[1] += r4.y; v[2] += r4.z; v[3] += r4.w;
            }
            if (addC) {
                float4 c4 = *(const float4*)&C[cidx];
                v[0] += c4.x; v[1] += c4.y; v[2] += c4.z; v[3] += c4.w;
            }
            *(float4*)&C[cidx] = make_float4(v[0], v[1], v[2], v[3]);
        }
    }
}

// ---------------------------------------------------------------- small kernels
__global__ __launch_bounds__(256) void k_zero(float* __restrict__ p, int n) {
    int i = blockIdx.x*256 + threadIdx.x;
    if (i < n) p[i] = 0.f;
}

// t1[b,n] += partial of x[b,:]@se_w1    grid (80, 8)
__global__ __launch_bounds__(256) void k_se1(const float* __restrict__ x,
    const float* __restrict__ w1, float* __restrict__ t1)
{
    const int blk = blockIdx.x, b = blockIdx.y, t = threadIdx.x;
    const int k0 = blk * 250;
    float acc = 0.f;
    for (int kk = 0; kk < 250; kk++) {
        float xv = x[b*Gg + k0 + kk];
        acc += xv * w1[(size_t)(k0 + kk)*256 + t];
    }
    atomicAdd(&t1[b*256 + t], acc);
}

// samp[b,d] = relu(t1+b1) @ w2 + b2     grid (8)
__global__ __launch_bounds__(256) void k_se2(const float* __restrict__ t1,
    const float* __restrict__ b1, const float* __restrict__ w2,
    const float* __restrict__ b2, float* __restrict__ samp)
{
    const int b = blockIdx.x, t = threadIdx.x;
    __shared__ float s1[256];
    s1[t] = fmaxf(t1[b*256 + t] + b1[t], 0.f);
    __syncthreads();
    float acc = 0.f;
    for (int n = 0; n < 256; n++) acc += s1[n] * w2[(size_t)n*256 + t];
    samp[b*256 + t] = acc + b2[t];
}

// o[g,d] = gene_emb[g,d] + ree(b,g,d) + samp[b,d]   grid (G), one batch
__global__ __launch_bounds__(256) void k_embed(const float* __restrict__ x,
    const float* __restrict__ gene_emb, const float* __restrict__ samp,
    float* __restrict__ outb, int b)
{
    const int g = blockIdx.x;
    const int d = threadIdx.x;
    const float xv = x[b*Gg + g];
    const int j = d & 127;
    float ang = xv * expf(-(float)j * 0.035977892078032f);  // ln(100)/128
    float ree = (d < 128) ? sinf(ang) : cosf(ang);
    if (xv == -10.0f) ree = 0.f;
    outb[(size_t)g*256 + d] = gene_emb[(size_t)g*256 + d] + ree + samp[b*256 + d];
}

// row LayerNorm over D=256. grid(rows), block 256.
__global__ __launch_bounds__(256) void k_ln(const float* __restrict__ src,
    float* __restrict__ dst, const float* __restrict__ gam,
    const float* __restrict__ bet)
{
    const size_t row = blockIdx.x;
    const int t = threadIdx.x;
    float v = src[row*256 + t];
    float s1 = v, s2 = v*v;
    for (int off = 32; off; off >>= 1) {
        s1 += __shfl_down(s1, off);
        s2 += __shfl_down(s2, off);
    }
    __shared__ float a1[4], a2[4];
    if ((t & 63) == 0) { a1[t >> 6] = s1; a2[t >> 6] = s2; }
    __syncthreads();
    float m1 = (a1[0]+a1[1]+a1[2]+a1[3]) * (1.f/256.f);
    float m2 = (a2[0]+a2[1]+a2[2]+a2[3]) * (1.f/256.f);
    float inv = rsqrtf(m2 - m1*m1 + 1e-5f);
    dst[row*256 + t] = (v - m1)*inv*gam[t] + bet[t];
}

// per-batch partial max of dd_k over a g-range.  grid (20, 8)
__global__ __launch_bounds__(256) void k_kmax(const float* __restrict__ kbuf,
    const float* __restrict__ proj, float* __restrict__ kmaxp)
{
    const int h = blockIdx.y, blk = blockIdx.x;
    const int t = threadIdx.x;
    __shared__ float ps[128][33];
    __shared__ float kt[64][33];
    for (int i = t; i < 4096; i += 256) ps[i >> 5][i & 31] = proj[i];
    const int rows = Gg / 20;   // 1000
    const int g0 = blk * rows;
    float mx = -1e30f;
    for (int gc = 0; gc < rows; gc += 64) {
        const int nr = min(64, rows - gc);
        __syncthreads();
        for (int i = t; i < 2048; i += 256) {
            int r = i >> 5, d = i & 31;
            kt[r][d] = (r < nr) ?
                kbuf[(size_t)(g0 + gc + r)*256 + h*32 + d] : 0.f;
        }
        __syncthreads();
        for (int i = t; i < nr*128; i += 256) {
            int r = i >> 7, mm = i & 127;
            float s = 0.f;
#pragma unroll
            for (int d = 0; d < 32; d++) s += kt[r][d]*ps[mm][d];
            mx = fmaxf(mx, s);
        }
    }
    mx *= 0.4204482076268573f;   // dn > 0: scale after max
    for (int off = 32; off; off >>= 1) mx = fmaxf(mx, __shfl_down(mx, off));
    __shared__ float sm[4];
    if ((t & 63) == 0) sm[t >> 6] = mx;
    __syncthreads();
    if (t == 0) kmaxp[h*32 + blk] = fmaxf(fmaxf(sm[0], sm[1]), fmaxf(sm[2], sm[3]));
}

__global__ void k_kmax_red(const float* __restrict__ kmaxp, float* __restrict__ kmax) {
    const int t = threadIdx.x;   // 64
    if (t < 8) {
        float m = -1e30f;
        for (int i = 0; i < 20; i++) m = fmaxf(m, kmaxp[t*32 + i]);
        kmax[t] = m;
    }
}

// ctx[h,m,dh] += sum_g kp[g,m]*v[g,dh]; ksum[h,m] += sum_g kp[g,m]   grid (8, 8)
__global__ __launch_bounds__(256) void k_ctx(
    const float* __restrict__ kbuf, const float* __restrict__ vbuf,
    const float* __restrict__ proj, const float* __restrict__ kmax,
    float* __restrict__ ctx_g, float* __restrict__ ksum_g)
{
    const int h = blockIdx.y, blk = blockIdx.x;
    const int t = threadIdx.x;
    __shared__ float ps[128][33];
    __shared__ float kt[32][33];
    __shared__ float vt[32][36];
    __shared__ float kp[32][128];
    __shared__ float diag[32];
    for (int i = t; i < 4096; i += 256) ps[i >> 5][i & 31] = proj[i];
    const float km = kmax[h];
    const int rows = Gg / 8;    // 2500
    const int g0 = blk * rows;
    const float dn    = 0.4204482076268573f;
    const float dn2h  = 0.5f * 0.17677669529663687f;
    const float ratio = 0.08838834764831845f;
    float acc[16];
#pragma unroll
    for (int j = 0; j < 16; j++) acc[j] = 0.f;
    float ksl = 0.f;
    const int m   = t & 127;
    const int dh0 = (t >> 7) * 16;
    for (int gc = 0; gc < rows; gc += 32) {
        const int nr = min(32, rows - gc);
        __syncthreads();
        for (int i = t; i < 1024; i += 256) {
            int r = i >> 5, d = i & 31;
            float kv = 0.f, vv = 0.f;
            if (r < nr) {
                size_t base = (size_t)(g0 + gc + r)*256 + h*32 + d;
                kv = kbuf[base]; vv = vbuf[base];
            }
            kt[r][d] = kv; vt[r][d] = vv;
        }
        __syncthreads();
        if (t < 32) {
            float s = 0.f;
#pragma unroll
            for (int d = 0; d < 32; d++) s += kt[t][d]*kt[t][d];
            diag[t] = dn2h * s;
        }
        __syncthreads();
        for (int i = t; i < 4096; i += 256) {
            int r = i >> 7, mm = i & 127;
            float val = 0.f;
            if (r < nr) {
                float s = 0.f;
#pragma unroll
                for (int d = 0; d < 32; d++) s += kt[r][d]*ps[mm][d];
                val = ratio * (expf(s*dn - diag[r] - km) + 1e-4f);
            }
            kp[r][mm] = val;
        }
        __syncthreads();
        for (int g = 0; g < nr; g++) {
            float kpv = kp[g][m];
            if (t < 128) ksl += kpv;
            const float4* vp = (const float4*)&vt[g][dh0];
            float4 v0 = vp[0], v1 = vp[1], v2 = vp[2], v3 = vp[3];
            acc[0]  += kpv*v0.x; acc[1]  += kpv*v0.y; acc[2]  += kpv*v0.z; acc[3]  += kpv*v0.w;
            acc[4]  += kpv*v1.x; acc[5]  += kpv*v1.y; acc[6]  += kpv*v1.z; acc[7]  += kpv*v1.w;
            acc[8]  += kpv*v2.x; acc[9]  += kpv*v2.y; acc[10] += kpv*v2.z; acc[11] += kpv*v2.w;
            acc[12] += kpv*v3.x; acc[13] += kpv*v3.y; acc[14] += kpv*v3.z; acc[15] += kpv*v3.w;
        }
    }
#pragma unroll
    for (int j = 0; j < 16; j++)
        atomicAdd(&ctx_g[((size_t)h*128 + m)*32 + dh0 + j], acc[j]);
    if (t < 128) atomicAdd(&ksum_g[h*128 + m], ksl);
}

// o[g,h*32+dh] = dinv * qp @ ctx      grid (16, 8); 4 lanes per row
__global__ __launch_bounds__(256) void k_attn(
    const float* __restrict__ qbuf, const float* __restrict__ ctx_g,
    const float* __restrict__ ksum_g, const float* __restrict__ proj,
    float* __restrict__ obuf)
{
    const int h = blockIdx.y, blk = blockIdx.x;
    const int t = threadIdx.x;
    __shared__ float ps[128][32];   // swizzled: col = (d + (m>>5)*8)&31
    __shared__ float cs[128][32];   // swizzled
    __shared__ float ks[128];
    __shared__ float qt[64][33];
    __shared__ float diag[64];
    for (int i = t; i < 4096; i += 256) {
        int mm = i >> 5, d = i & 31;
        int c = (d + (mm >> 5)*8) & 31;
        ps[mm][c] = proj[i];
        cs[mm][c] = ctx_g[(size_t)h*4096 + i];
    }
    if (t < 128) ks[t] = ksum_g[h*128 + t];
    const int rows = Gg / 16;   // 1250
    const int g0 = blk * rows;
    const int sub = t & 3, r = t >> 2;
    const int mbase = sub * 32;
    const int swz = sub * 8;
    const float dn    = 0.4204482076268573f;
    const float dn2h  = 0.5f * 0.17677669529663687f;
    const float ratio = 0.08838834764831845f;
    for (int gc = 0; gc < rows; gc += 64) {
        const int nr = min(64, rows - gc);
        __syncthreads();
        for (int i = t; i < 2048; i += 256) {
            int rr = i >> 5, d = i & 31;
            qt[rr][d] = (rr < nr) ?
                qbuf[(size_t)(g0 + gc + rr)*256 + h*32 + d] : 0.f;
        }
        __syncthreads();
        if (t < 64) {
            float s = 0.f;
#pragma unroll
            for (int d = 0; d < 32; d++) s += qt[t][d]*qt[t][d];
            diag[t] = dn2h * s;
        }
        __syncthreads();
        float dd[32];
        float mx = -1e30f;
#pragma unroll 4
        for (int j = 0; j < 32; j++) {
            float s = 0.f;
#pragma unroll
            for (int d = 0; d < 32; d++) s += qt[r][d] * ps[mbase + j][(d + swz) & 31];
            dd[j] = s * dn;
            mx = fmaxf(mx, dd[j]);
        }
        mx = fmaxf(mx, __shfl_xor(mx, 1));
        mx = fmaxf(mx, __shfl_xor(mx, 2));
        float den = 0.f;
#pragma unroll 4
        for (int j = 0; j < 32; j++) {
            float p = ratio * (expf(dd[j] - diag[r] - mx) + 1e-4f);
            dd[j] = p;
            den += p * ks[mbase + j];
        }
        den += __shfl_xor(den, 1);
        den += __shfl_xor(den, 2);
        float dinv = 1.f / den;
        float oa[32];
#pragma unroll
        for (int d = 0; d < 32; d++) oa[d] = 0.f;
#pragma unroll 4
        for (int j = 0; j < 32; j++) {
            float p = dd[j];
#pragma unroll
            for (int d = 0; d < 32; d++) oa[d] += p * cs[mbase + j][(d + swz) & 31];
        }
#pragma unroll
        for (int d = 0; d < 32; d++) {
            oa[d] += __shfl_xor(oa[d], 1);
            oa[d] += __shfl_xor(oa[d], 2);
        }
        if (r < nr) {
            size_t base = (size_t)(g0 + gc + r)*256 + h*32;
#pragma unroll
            for (int jj = 0; jj < 8; jj++)
                obuf[base + sub*8 + jj] = dinv * oa[sub*8 + jj];
        }
    }
}

// out[row] = relu(u[row,:] @ w2 + b2)    grid (rows)
__global__ __launch_bounds__(256) void k_head(const float* __restrict__ u,
    const float* __restrict__ w2, const float* __restrict__ b2,
    float* __restrict__ outp)
{
    const int row = blockIdx.x;
    const int t = threadIdx.x;
    float a = 0.f;
#pragma unroll
    for (int j = 0; j < 4; j++)
        a += u[(size_t)row*1024 + t + j*256] * w2[t + j*256];
    for (int off = 32; off; off >>= 1) a += __shfl_down(a, off);
    __shared__ float sm[4];
    if ((t & 63) == 0) sm[t >> 6] = a;
    __syncthreads();
    if (t == 0)
        outp[row] = fmaxf(sm[0] + sm[1] + sm[2] + sm[3] + b2[0], 0.f);
}

// ---------------------------------------------------------------- launch
extern "C" void kernel_launch(void* const* d_in, const int* in_sizes, int n_in,
                              void* d_out, int out_size, void* d_ws, size_t ws_size,
                              hipStream_t stream)
{
    const float* x        = (const float*)d_in[0];
    const float* gene_emb = (const float*)d_in[1];
    const float* se_w1    = (const float*)d_in[2];
    const float* se_b1    = (const float*)d_in[3];
    const float* se_w2    = (const float*)d_in[4];
    const float* se_b2    = (const float*)d_in[5];
    const float* proj_w1  = (const float*)d_in[6];
    const float* proj_b1  = (const float*)d_in[7];
    const float* proj_w2  = (const float*)d_in[8];
    const float* proj_b2  = (const float*)d_in[9];
    const float* ln1_g    = (const float*)d_in[10];
    const float* ln1_b    = (const float*)d_in[11];
    const float* wq       = (const float*)d_in[12];
    const float* wk       = (const float*)d_in[13];
    const float* wv       = (const float*)d_in[14];
    const float* wo       = (const float*)d_in[15];
    const float* bo       = (const float*)d_in[16];
    const float* ln2_g    = (const float*)d_in[17];
    const float* ln2_b    = (const float*)d_in[18];
    const float* ff_w1    = (const float*)d_in[19];
    const float* ff_b1    = (const float*)d_in[20];
    const float* ff_w2    = (const float*)d_in[21];
    const float* ff_b2    = (const float*)d_in[22];
    const float* featp    = (const float*)d_in[23];
    const float* norm_g   = (const float*)d_in[24];
    const float* norm_b   = (const float*)d_in[25];
    const float* head_w1  = (const float*)d_in[26];
    const float* head_b1  = (const float*)d_in[27];
    const float* head_w2  = (const float*)d_in[28];
    const float* head_b2  = (const float*)d_in[29];
    float* out = (float*)d_out;

    // workspace: ~23.1M floats (92.3 MB)
    float* w = (float*)d_ws;
    const size_t SB = (size_t)Gg * Dd;        // 5,120,000 floats
    float* f_h = w;                            // [G,D] current batch h
    float* B1  = f_h + SB;                     // [G,D]
    float* B2  = B1  + SB;                     // [G,D]
    float* B3  = B2  + SB;                     // [G,D]
    float* B4  = B3  + SB;                     // [CHK,FF] = 2,560,000
    float* smw   = B4 + (size_t)CHK * FFf;
    float* t1    = smw;                        // 2048
    float* samp  = t1 + 2048;                  // 2048
    float* ctx   = samp + 2048;                // 8*128*32 = 32768
    float* ksum  = ctx + 32768;                // 1024
    float* kmaxp = ksum + 1024;                // 256
    float* kmax  = kmaxp + 256;                // 8

    auto gemm = [&](const float* A, const float* Bw, const float* bias,
                    const float* res, float* C, int Mr, int N, int K,
                    int act, int addC) {
        dim3 grid(N/128, (Mr + 127)/128);
        gemm128<<<grid, 256, 0, stream>>>(A, Bw, bias, res, C, Mr, N, K, act, addC);
    };

    // ---- sample embedding for all batches (tiny)
    k_zero<<<8, 256, 0, stream>>>(t1, 2048);
    k_se1<<<dim3(80, 8), 256, 0, stream>>>(x, se_w1, t1);
    k_se2<<<8, 256, 0, stream>>>(t1, se_b1, se_w2, se_b2, samp);

    // ---- per batch: full network
    for (int b = 0; b < Bb; b++) {
        // prologue: embed -> B1; h = MLP(B1)
        k_embed<<<Gg, 256, 0, stream>>>(x, gene_emb, samp, B1, b);
        for (int c = 0; c < 8; c++) {
            size_t off = (size_t)c * CHK * Dd;
            gemm(B1 + off, proj_w1, proj_b1, nullptr, B4, CHK, FFf, Dd, 1, 0);
            gemm(B4, proj_w2, proj_b2, nullptr, f_h + off, CHK, Dd, FFf, 0, 0);
        }
        // layers
        for (int l = 0; l < Ll; l++) {
            const float* pwq = wq + (size_t)l*Dd*Dd;
            const float* pwk = wk + (size_t)l*Dd*Dd;
            const float* pwv = wv + (size_t)l*Dd*Dd;
            const float* pwo = wo + (size_t)l*Dd*Dd;
            const float* pproj = featp + (size_t)l*Mm*DHh;

            k_ln<<<Gg, 256, 0, stream>>>(f_h, B1, ln1_g + l*Dd, ln1_b + l*Dd);
            gemm(B1, pwk, nullptr, nullptr, B2, Gg, Dd, Dd, 0, 0);       // k
            k_kmax<<<dim3(20, 8), 256, 0, stream>>>(B2, pproj, kmaxp);
            k_kmax_red<<<1, 64, 0, stream>>>(kmaxp, kmax);
            gemm(B1, pwv, nullptr, nullptr, B3, Gg, Dd, Dd, 0, 0);       // v
            k_zero<<<132, 256, 0, stream>>>(ctx, 32768 + 1024);
            k_ctx<<<dim3(8, 8), 256, 0, stream>>>(B2, B3, pproj, kmax, ctx, ksum);
            gemm(B1, pwq, nullptr, nullptr, B2, Gg, Dd, Dd, 0, 0);       // q (k dead)
            k_attn<<<dim3(16, 8), 256, 0, stream>>>(B2, ctx, ksum, pproj, B3); // o (v dead)
            gemm(B3, pwo, bo + l*Dd, f_h, B1, Gg, Dd, Dd, 0, 0);         // y (a dead)
            k_ln<<<Gg, 256, 0, stream>>>(B1, B2, ln2_g + l*Dd, ln2_b + l*Dd); // f
            for (int c = 0; c < 8; c++) {
                size_t off = (size_t)c * CHK * Dd;
                gemm(B2 + off, ff_w1 + (size_t)l*Dd*FFf, ff_b1 + l*FFf,
                     nullptr, B4, CHK, FFf, Dd, 2, 0);
                // h_chunk = old_h + y_chunk + B4@ffw2 + b2
                gemm(B4, ff_w2 + (size_t)l*FFf*Dd, ff_b2 + l*Dd,
                     B1 + off, f_h + off, CHK, Dd, FFf, 0, 1);
            }
        }
        // head
        k_ln<<<Gg, 256, 0, stream>>>(f_h, B1, norm_g, norm_b);
        for (int c = 0; c < 8; c++) {
            size_t off = (size_t)c * CHK * Dd;
            gemm(B1 + off, head_w1, head_b1, nullptr, B4, CHK, FFf, Dd, 1, 0);
            k_head<<<CHK, 256, 0, stream>>>(B4, head_w2, head_b2,
                                            out + b*Gg + c*CHK);
        }
    }
}

// Round 4
// 31350.412 us; speedup vs baseline: 3.8199x; 3.8199x over previous
//
#include <hip/hip_runtime.h>

// SimplePerformer forward: bf16-MFMA GEMMs + fp32 FAVOR+ attention.
// B=8 G=20000 D=256 H=8 DH=32 L=4 M=128 FF=1024
#define Bb 8
#define Gg 20000
#define Dd 256
#define Hh 8
#define DHh 32
#define Ll 4
#define Mm 128
#define FFf 1024

typedef __attribute__((ext_vector_type(8))) short bf16x8;
typedef __attribute__((ext_vector_type(4))) float f32x4;

__device__ __forceinline__ float geluf(float x) {
    return 0.5f * x * (1.0f + erff(x * 0.70710678118654752f));
}
__device__ __forceinline__ float bf2f(ushort u) {
    union { uint i; float f; } v; v.i = ((uint)u) << 16; return v.f;
}
__device__ __forceinline__ ushort f2bf(float f) {
    union { float f; uint i; } v; v.f = f;
    uint i = v.i;
    return (ushort)((i + 0x7FFFu + ((i >> 16) & 1u)) >> 16);   // RNE
}

// ------------------------------------------------- weight transpose-cast
// src [K,N] fp32 -> dst [N,K] bf16.  grid (N/32, K/32), block 256 (32x8)
__global__ __launch_bounds__(256) void k_wt(const float* __restrict__ src,
    ushort* __restrict__ dst, int K, int N)
{
    __shared__ float tl[32][33];
    const int n0 = blockIdx.x * 32, k0 = blockIdx.y * 32;
    const int tx = threadIdx.x & 31, ty = threadIdx.x >> 5;   // ty 0..7
#pragma unroll
    for (int i = 0; i < 4; i++)
        tl[ty + i*8][tx] = src[(size_t)(k0 + ty + i*8) * N + n0 + tx];
    __syncthreads();
#pragma unroll
    for (int i = 0; i < 4; i++)
        dst[(size_t)(n0 + ty + i*8) * K + k0 + tx] = f2bf(tl[tx][ty + i*8]);
}

// ------------------------------------------------- bf16 MFMA GEMM 128x128
// C = act(A@B + bias) [+res] [+C_old];  A [Mrows,K] bf16, Bt [N,K] bf16.
// grid (N/128, ceil(Mrows/128)), block 256 (4 waves, 2x2 of 64x64).
template<int CBF>
__global__ __launch_bounds__(256) void gemm_bf(
    const ushort* __restrict__ A, const ushort* __restrict__ Bt,
    const float* __restrict__ bias, const float* __restrict__ res,
    void* __restrict__ Cv, int Mrows, int N, int K, int act, int addC)
{
    __shared__ ushort As[128][40];
    __shared__ ushort Bs[128][40];
    const int t = threadIdx.x;
    const int row0 = blockIdx.y * 128;
    const int col0 = blockIdx.x * 128;
    const int l  = t & 63, wid = t >> 6;
    const int wr = (wid & 1) * 64, wc = (wid >> 1) * 64;
    const int lr = l & 15, ko8 = (l >> 4) * 8;

    const int sr = t >> 1;               // 0..127
    const int sh = (t & 1) * 16;         // k offset 0/16
    const int ra = min(row0 + sr, Mrows - 1);
    const ushort* pA = A  + (size_t)ra * K + sh;
    const ushort* pB = Bt + (size_t)(col0 + sr) * K + sh;

    f32x4 acc[4][4] = {};

    for (int k0 = 0; k0 < K; k0 += 32) {
        uint4 av0 = *(const uint4*)(pA + k0);
        uint4 av1 = *(const uint4*)(pA + k0 + 8);
        uint4 bv0 = *(const uint4*)(pB + k0);
        uint4 bv1 = *(const uint4*)(pB + k0 + 8);
        __syncthreads();
        *(uint4*)&As[sr][sh]     = av0;
        *(uint4*)&As[sr][sh + 8] = av1;
        *(uint4*)&Bs[sr][sh]     = bv0;
        *(uint4*)&Bs[sr][sh + 8] = bv1;
        __syncthreads();
        bf16x8 af[4];
#pragma unroll
        for (int mi = 0; mi < 4; mi++)
            af[mi] = *(const bf16x8*)&As[wr + mi*16 + lr][ko8];
#pragma unroll
        for (int ni = 0; ni < 4; ni++) {
            bf16x8 bfv = *(const bf16x8*)&Bs[wc + ni*16 + lr][ko8];
#pragma unroll
            for (int mi = 0; mi < 4; mi++)
                acc[mi][ni] = __builtin_amdgcn_mfma_f32_16x16x32_bf16(
                    af[mi], bfv, acc[mi][ni], 0, 0, 0);
        }
    }

    const int rg = (l >> 4) * 4;
#pragma unroll
    for (int mi = 0; mi < 4; mi++) {
#pragma unroll
        for (int j = 0; j < 4; j++) {
            int row = row0 + wr + mi*16 + rg + j;
            if (row >= Mrows) continue;
#pragma unroll
            for (int ni = 0; ni < 4; ni++) {
                int col = col0 + wc + ni*16 + lr;
                float v = acc[mi][ni][j];
                if (bias) v += bias[col];
                if (act == 1) v = fmaxf(v, 0.f);
                else if (act == 2) v = geluf(v);
                size_t ci = (size_t)row * N + col;
                if (res) v += res[ci];
                if (CBF) {
                    ((ushort*)Cv)[ci] = f2bf(v);
                } else {
                    float* C = (float*)Cv;
                    if (addC) v += C[ci];
                    C[ci] = v;
                }
            }
        }
    }
}

// ------------------------------------------------- small kernels
__global__ __launch_bounds__(256) void k_zero(float* __restrict__ p, int n) {
    int i = blockIdx.x*256 + threadIdx.x;
    if (i < n) p[i] = 0.f;
}

__global__ __launch_bounds__(256) void k_se1(const float* __restrict__ x,
    const float* __restrict__ w1, float* __restrict__ t1)
{
    const int blk = blockIdx.x, b = blockIdx.y, t = threadIdx.x;
    const int k0 = blk * 250;
    float acc = 0.f;
    for (int kk = 0; kk < 250; kk++) {
        float xv = x[b*Gg + k0 + kk];
        acc += xv * w1[(size_t)(k0 + kk)*256 + t];
    }
    atomicAdd(&t1[b*256 + t], acc);
}

__global__ __launch_bounds__(256) void k_se2(const float* __restrict__ t1,
    const float* __restrict__ b1, const float* __restrict__ w2,
    const float* __restrict__ b2, float* __restrict__ samp)
{
    const int b = blockIdx.x, t = threadIdx.x;
    __shared__ float s1[256];
    s1[t] = fmaxf(t1[b*256 + t] + b1[t], 0.f);
    __syncthreads();
    float acc = 0.f;
    for (int n = 0; n < 256; n++) acc += s1[n] * w2[(size_t)n*256 + t];
    samp[b*256 + t] = acc + b2[t];
}

// embed -> bf16.  grid (G)
__global__ __launch_bounds__(256) void k_embed(const float* __restrict__ x,
    const float* __restrict__ gene_emb, const float* __restrict__ samp,
    ushort* __restrict__ outb, int b)
{
    const int g = blockIdx.x;
    const int d = threadIdx.x;
    const float xv = x[b*Gg + g];
    const int j = d & 127;
    float ang = xv * expf(-(float)j * 0.035977892078032f);   // ln(100)/128
    float ree = (d < 128) ? sinf(ang) : cosf(ang);
    if (xv == -10.0f) ree = 0.f;
    outb[(size_t)g*256 + d] =
        f2bf(gene_emb[(size_t)g*256 + d] + ree + samp[b*256 + d]);
}

// LayerNorm, fp32 src -> bf16 dst.  grid(rows)
__global__ __launch_bounds__(256) void k_ln(const float* __restrict__ src,
    ushort* __restrict__ dst, const float* __restrict__ gam,
    const float* __restrict__ bet)
{
    const size_t row = blockIdx.x;
    const int t = threadIdx.x;
    float v = src[row*256 + t];
    float s1 = v, s2 = v*v;
    for (int off = 32; off; off >>= 1) {
        s1 += __shfl_down(s1, off);
        s2 += __shfl_down(s2, off);
    }
    __shared__ float a1[4], a2[4];
    if ((t & 63) == 0) { a1[t >> 6] = s1; a2[t >> 6] = s2; }
    __syncthreads();
    float m1 = (a1[0]+a1[1]+a1[2]+a1[3]) * (1.f/256.f);
    float m2 = (a2[0]+a2[1]+a2[2]+a2[3]) * (1.f/256.f);
    float inv = rsqrtf(m2 - m1*m1 + 1e-5f);
    dst[row*256 + t] = f2bf((v - m1)*inv*gam[t] + bet[t]);
}

// global max of dd_k.  grid (20, 8)
__global__ __launch_bounds__(256) void k_kmax(const ushort* __restrict__ kbuf,
    const float* __restrict__ proj, float* __restrict__ kmaxp)
{
    const int h = blockIdx.y, blk = blockIdx.x;
    const int t = threadIdx.x;
    __shared__ float ps[128][33];
    __shared__ float kt[64][33];
    for (int i = t; i < 4096; i += 256) ps[i >> 5][i & 31] = proj[i];
    const int rows = 1000;
    const int g0 = blk * rows;
    float mx = -1e30f;
    for (int gc = 0; gc < rows; gc += 64) {
        const int nr = min(64, rows - gc);
        __syncthreads();
        for (int i = t; i < 2048; i += 256) {
            int r = i >> 5, d = i & 31;
            kt[r][d] = (r < nr) ?
                bf2f(kbuf[(size_t)(g0 + gc + r)*256 + h*32 + d]) : 0.f;
        }
        __syncthreads();
        for (int i = t; i < nr*128; i += 256) {
            int r = i >> 7, mm = i & 127;
            float s = 0.f;
#pragma unroll
            for (int d = 0; d < 32; d++) s += kt[r][d]*ps[mm][d];
            mx = fmaxf(mx, s);
        }
    }
    mx *= 0.4204482076268573f;
    for (int off = 32; off; off >>= 1) mx = fmaxf(mx, __shfl_down(mx, off));
    __shared__ float sm[4];
    if ((t & 63) == 0) sm[t >> 6] = mx;
    __syncthreads();
    if (t == 0) kmaxp[h*32 + blk] = fmaxf(fmaxf(sm[0], sm[1]), fmaxf(sm[2], sm[3]));
}

__global__ void k_kmax_red(const float* __restrict__ kmaxp, float* __restrict__ kmax) {
    const int t = threadIdx.x;
    if (t < 8) {
        float m = -1e30f;
        for (int i = 0; i < 20; i++) m = fmaxf(m, kmaxp[t*32 + i]);
        kmax[t] = m;
    }
}

// ctx/ksum accumulation.  grid (32, 8)
__global__ __launch_bounds__(256) void k_ctx(
    const ushort* __restrict__ kbuf, const ushort* __restrict__ vbuf,
    const float* __restrict__ proj, const float* __restrict__ kmax,
    float* __restrict__ ctx_g, float* __restrict__ ksum_g)
{
    const int h = blockIdx.y, blk = blockIdx.x;
    const int t = threadIdx.x;
    __shared__ float ps[128][33];
    __shared__ float kt[32][33];
    __shared__ float vt[32][36];
    __shared__ float kp[32][128];
    __shared__ float diag[32];
    for (int i = t; i < 4096; i += 256) ps[i >> 5][i & 31] = proj[i];
    const float km = kmax[h];
    const int rows = 625;
    const int g0 = blk * rows;
    const float dn    = 0.4204482076268573f;
    const float dn2h  = 0.5f * 0.17677669529663687f;
    const float ratio = 0.08838834764831845f;
    float acc[16];
#pragma unroll
    for (int j = 0; j < 16; j++) acc[j] = 0.f;
    float ksl = 0.f;
    const int m   = t & 127;
    const int dh0 = (t >> 7) * 16;
    for (int gc = 0; gc < rows; gc += 32) {
        const int nr = min(32, rows - gc);
        __syncthreads();
        for (int i = t; i < 1024; i += 256) {
            int r = i >> 5, d = i & 31;
            float kv = 0.f, vv = 0.f;
            if (r < nr) {
                size_t base = (size_t)(g0 + gc + r)*256 + h*32 + d;
                kv = bf2f(kbuf[base]); vv = bf2f(vbuf[base]);
            }
            kt[r][d] = kv; vt[r][d] = vv;
        }
        __syncthreads();
        if (t < 32) {
            float s = 0.f;
#pragma unroll
            for (int d = 0; d < 32; d++) s += kt[t][d]*kt[t][d];
            diag[t] = dn2h * s;
        }
        __syncthreads();
        for (int i = t; i < 4096; i += 256) {
            int r = i >> 7, mm = i & 127;
            float val = 0.f;
            if (r < nr) {
                float s = 0.f;
#pragma unroll
                for (int d = 0; d < 32; d++) s += kt[r][d]*ps[mm][d];
                val = ratio * (expf(s*dn - diag[r] - km) + 1e-4f);
            }
            kp[r][mm] = val;
        }
        __syncthreads();
        for (int g = 0; g < nr; g++) {
            float kpv = kp[g][m];
            if (t < 128) ksl += kpv;
            const float4* vp = (const float4*)&vt[g][dh0];
            float4 v0 = vp[0], v1 = vp[1], v2 = vp[2], v3 = vp[3];
            acc[0]  += kpv*v0.x; acc[1]  += kpv*v0.y; acc[2]  += kpv*v0.z; acc[3]  += kpv*v0.w;
            acc[4]  += kpv*v1.x; acc[5]  += kpv*v1.y; acc[6]  += kpv*v1.z; acc[7]  += kpv*v1.w;
            acc[8]  += kpv*v2.x; acc[9]  += kpv*v2.y; acc[10] += kpv*v2.z; acc[11] += kpv*v2.w;
            acc[12] += kpv*v3.x; acc[13] += kpv*v3.y; acc[14] += kpv*v3.z; acc[15] += kpv*v3.w;
        }
    }
#pragma unroll
    for (int j = 0; j < 16; j++)
        atomicAdd(&ctx_g[((size_t)h*128 + m)*32 + dh0 + j], acc[j]);
    if (t < 128) atomicAdd(&ksum_g[h*128 + m], ksl);
}

// qp @ ctx with dinv.  grid (32, 8); 4 lanes per row; bf16 out.
__global__ __launch_bounds__(256) void k_attn(
    const ushort* __restrict__ qbuf, const float* __restrict__ ctx_g,
    const float* __restrict__ ksum_g, const float* __restrict__ proj,
    ushort* __restrict__ obuf)
{
    const int h = blockIdx.y, blk = blockIdx.x;
    const int t = threadIdx.x;
    __shared__ float ps[128][32];
    __shared__ float cs[128][32];
    __shared__ float ks[128];
    __shared__ float qt[64][33];
    __shared__ float diag[64];
    for (int i = t; i < 4096; i += 256) {
        int mm = i >> 5, d = i & 31;
        int c = (d + (mm >> 5)*8) & 31;
        ps[mm][c] = proj[i];
        cs[mm][c] = ctx_g[(size_t)h*4096 + i];
    }
    if (t < 128) ks[t] = ksum_g[h*128 + t];
    const int rows = 625;
    const int g0 = blk * rows;
    const int sub = t & 3, r = t >> 2;
    const int mbase = sub * 32;
    const int swz = sub * 8;
    const float dn    = 0.4204482076268573f;
    const float dn2h  = 0.5f * 0.17677669529663687f;
    const float ratio = 0.08838834764831845f;
    for (int gc = 0; gc < rows; gc += 64) {
        const int nr = min(64, rows - gc);
        __syncthreads();
        for (int i = t; i < 2048; i += 256) {
            int rr = i >> 5, d = i & 31;
            qt[rr][d] = (rr < nr) ?
                bf2f(qbuf[(size_t)(g0 + gc + rr)*256 + h*32 + d]) : 0.f;
        }
        __syncthreads();
        if (t < 64) {
            float s = 0.f;
#pragma unroll
            for (int d = 0; d < 32; d++) s += qt[t][d]*qt[t][d];
            diag[t] = dn2h * s;
        }
        __syncthreads();
        float dd[32];
        float mx = -1e30f;
#pragma unroll 4
        for (int j = 0; j < 32; j++) {
            float s = 0.f;
#pragma unroll
            for (int d = 0; d < 32; d++) s += qt[r][d] * ps[mbase + j][(d + swz) & 31];
            dd[j] = s * dn;
            mx = fmaxf(mx, dd[j]);
        }
        mx = fmaxf(mx, __shfl_xor(mx, 1));
        mx = fmaxf(mx, __shfl_xor(mx, 2));
        float den = 0.f;
#pragma unroll 4
        for (int j = 0; j < 32; j++) {
            float p = ratio * (expf(dd[j] - diag[r] - mx) + 1e-4f);
            dd[j] = p;
            den += p * ks[mbase + j];
        }
        den += __shfl_xor(den, 1);
        den += __shfl_xor(den, 2);
        float dinv = 1.f / den;
        float oa[32];
#pragma unroll
        for (int d = 0; d < 32; d++) oa[d] = 0.f;
#pragma unroll 4
        for (int j = 0; j < 32; j++) {
            float p = dd[j];
#pragma unroll
            for (int d = 0; d < 32; d++) oa[d] += p * cs[mbase + j][(d + swz) & 31];
        }
#pragma unroll
        for (int d = 0; d < 32; d++) {
            oa[d] += __shfl_xor(oa[d], 1);
            oa[d] += __shfl_xor(oa[d], 2);
        }
        if (r < nr) {
            size_t base = (size_t)(g0 + gc + r)*256 + h*32;
#pragma unroll
            for (int jj = 0; jj < 8; jj++)
                obuf[base + sub*8 + jj] = f2bf(dinv * oa[sub*8 + jj]);
        }
    }
}

// head second layer: out[row] = relu(u[row,:]@w2 + b2).  grid (rows)
__global__ __launch_bounds__(256) void k_head(const ushort* __restrict__ u,
    const float* __restrict__ w2, const float* __restrict__ b2,
    float* __restrict__ outp)
{
    const int row = blockIdx.x;
    const int t = threadIdx.x;
    float a = 0.f;
#pragma unroll
    for (int j = 0; j < 4; j++)
        a += bf2f(u[(size_t)row*1024 + t + j*256]) * w2[t + j*256];
    for (int off = 32; off; off >>= 1) a += __shfl_down(a, off);
    __shared__ float sm[4];
    if ((t & 63) == 0) sm[t >> 6] = a;
    __syncthreads();
    if (t == 0)
        outp[row] = fmaxf(sm[0] + sm[1] + sm[2] + sm[3] + b2[0], 0.f);
}

// ---------------------------------------------------------------- launch
extern "C" void kernel_launch(void* const* d_in, const int* in_sizes, int n_in,
                              void* d_out, int out_size, void* d_ws, size_t ws_size,
                              hipStream_t stream)
{
    const float* x        = (const float*)d_in[0];
    const float* gene_emb = (const float*)d_in[1];
    const float* se_w1    = (const float*)d_in[2];
    const float* se_b1    = (const float*)d_in[3];
    const float* se_w2    = (const float*)d_in[4];
    const float* se_b2    = (const float*)d_in[5];
    const float* proj_w1  = (const float*)d_in[6];
    const float* proj_b1  = (const float*)d_in[7];
    const float* proj_w2  = (const float*)d_in[8];
    const float* proj_b2  = (const float*)d_in[9];
    const float* ln1_g    = (const float*)d_in[10];
    const float* ln1_b    = (const float*)d_in[11];
    const float* wq       = (const float*)d_in[12];
    const float* wk       = (const float*)d_in[13];
    const float* wv       = (const float*)d_in[14];
    const float* wo       = (const float*)d_in[15];
    const float* bo       = (const float*)d_in[16];
    const float* ln2_g    = (const float*)d_in[17];
    const float* ln2_b    = (const float*)d_in[18];
    const float* ff_w1    = (const float*)d_in[19];
    const float* ff_b1    = (const float*)d_in[20];
    const float* ff_w2    = (const float*)d_in[21];
    const float* ff_b2    = (const float*)d_in[22];
    const float* featp    = (const float*)d_in[23];
    const float* norm_g   = (const float*)d_in[24];
    const float* norm_b   = (const float*)d_in[25];
    const float* head_w1  = (const float*)d_in[26];
    const float* head_b1  = (const float*)d_in[27];
    const float* head_w2  = (const float*)d_in[28];
    const float* head_b2  = (const float*)d_in[29];
    float* out = (float*)d_out;

    // ---------------- workspace layout (85 MB base; B4 grows if room)
    float* w = (float*)d_ws;
    const size_t SB = (size_t)Gg * Dd;          // 5,120,000
    float* f_h = w;                              // [G,D] fp32
    float* B1  = w + SB;                         // [G,D] fp32 (y)
    float* t1    = w + 2*SB;                     // 2048
    float* samp  = t1 + 2048;                    // 2048
    float* ctx   = samp + 2048;                  // 32768
    float* ksum  = ctx + 32768;                  // 1024
    float* kmaxp = ksum + 1024;                  // 256
    float* kmax  = kmaxp + 256;                  // 8
    ushort* ub = (ushort*)(w + 2*SB + 40000);
    ushort* Ab = ub;                             // [G,D] bf16 (ln/embed/o)
    ushort* Kb = Ab + SB;                        // [G,D] bf16 (k then q)
    ushort* Vb = Kb + SB;                        // [G,D] bf16 (v)
    ushort* Wt = Vb + SB;                        // 4,000,000 bf16 weights
    ushort* B4 = Wt + 4000000;                   // [CHKR,FF] bf16

    // adaptive FF chunk size
    const int CHKR = (ws_size >= (size_t)121000000) ? Gg : 2500;
    const int NCH  = Gg / CHKR;

    auto gemm = [&](int CBF, const ushort* A, const ushort* Bw,
                    const float* bias, const float* res, void* C,
                    int Mr, int N, int K, int act, int addC) {
        dim3 grid(N/128, (Mr + 127)/128);
        if (CBF) gemm_bf<1><<<grid, 256, 0, stream>>>(A, Bw, bias, res, C, Mr, N, K, act, addC);
        else     gemm_bf<0><<<grid, 256, 0, stream>>>(A, Bw, bias, res, C, Mr, N, K, act, addC);
    };
    auto castw = [&](const float* src, ushort* dst, int K, int N) {
        k_wt<<<dim3(N/32, K/32), 256, 0, stream>>>(src, dst, K, N);
    };

    // ---------------- weight casts (bf16, transposed [N,K])
    const size_t LW = 786432;   // per-layer Wt stride
    for (int l = 0; l < Ll; l++) {
        castw(wq + (size_t)l*65536,    Wt + l*LW,          256, 256);
        castw(wk + (size_t)l*65536,    Wt + l*LW + 65536,  256, 256);
        castw(wv + (size_t)l*65536,    Wt + l*LW + 131072, 256, 256);
        castw(wo + (size_t)l*65536,    Wt + l*LW + 196608, 256, 256);
        castw(ff_w1 + (size_t)l*262144, Wt + l*LW + 262144, 256, 1024);
        castw(ff_w2 + (size_t)l*262144, Wt + l*LW + 524288, 1024, 256);
    }
    ushort* pj1T = Wt + 4*LW;            // [1024,256]
    ushort* pj2T = pj1T + 262144;        // [256,1024]
    ushort* hd1T = pj2T + 262144;        // [1024,256]
    castw(proj_w1, pj1T, 256, 1024);
    castw(proj_w2, pj2T, 1024, 256);
    castw(head_w1, hd1T, 256, 1024);

    // ---------------- sample embedding (all batches)
    k_zero<<<8, 256, 0, stream>>>(t1, 2048);
    k_se1<<<dim3(80, 8), 256, 0, stream>>>(x, se_w1, t1);
    k_se2<<<8, 256, 0, stream>>>(t1, se_b1, se_w2, se_b2, samp);

    // ---------------- per batch full network
    for (int b = 0; b < Bb; b++) {
        k_embed<<<Gg, 256, 0, stream>>>(x, gene_emb, samp, Ab, b);
        for (int c = 0; c < NCH; c++) {
            size_t off = (size_t)c * CHKR * Dd;
            gemm(1, Ab + off, pj1T, proj_b1, nullptr, B4, CHKR, FFf, Dd, 1, 0);
            gemm(0, B4, pj2T, proj_b2, nullptr, f_h + off, CHKR, Dd, FFf, 0, 0);
        }
        for (int l = 0; l < Ll; l++) {
            const ushort* qT = Wt + l*LW;
            const ushort* kT = qT + 65536;
            const ushort* vT = qT + 131072;
            const ushort* oT = qT + 196608;
            const ushort* f1T = qT + 262144;
            const ushort* f2T = qT + 524288;
            const float* pproj = featp + (size_t)l*Mm*DHh;

            k_ln<<<Gg, 256, 0, stream>>>(f_h, Ab, ln1_g + l*Dd, ln1_b + l*Dd);
            gemm(1, Ab, kT, nullptr, nullptr, Kb, Gg, Dd, Dd, 0, 0);      // k
            k_kmax<<<dim3(20, 8), 256, 0, stream>>>(Kb, pproj, kmaxp);
            k_kmax_red<<<1, 64, 0, stream>>>(kmaxp, kmax);
            gemm(1, Ab, vT, nullptr, nullptr, Vb, Gg, Dd, Dd, 0, 0);      // v
            k_zero<<<132, 256, 0, stream>>>(ctx, 32768 + 1024);
            k_ctx<<<dim3(32, 8), 256, 0, stream>>>(Kb, Vb, pproj, kmax, ctx, ksum);
            gemm(1, Ab, qT, nullptr, nullptr, Kb, Gg, Dd, Dd, 0, 0);      // q (k dead)
            k_attn<<<dim3(32, 8), 256, 0, stream>>>(Kb, ctx, ksum, pproj, Ab); // o (ln1 dead)
            gemm(0, Ab, oT, bo + l*Dd, f_h, B1, Gg, Dd, Dd, 0, 0);        // y fp32
            k_ln<<<Gg, 256, 0, stream>>>(B1, Ab, ln2_g + l*Dd, ln2_b + l*Dd);
            for (int c = 0; c < NCH; c++) {
                size_t off = (size_t)c * CHKR * Dd;
                gemm(1, Ab + off, f1T, ff_b1 + l*FFf, nullptr, B4, CHKR, FFf, Dd, 2, 0);
                gemm(0, B4, f2T, ff_b2 + l*Dd, B1 + off, f_h + off, CHKR, Dd, FFf, 0, 1);
            }
        }
        k_ln<<<Gg, 256, 0, stream>>>(f_h, Ab, norm_g, norm_b);
        for (int c = 0; c < NCH; c++) {
            size_t off = (size_t)c * CHKR * Dd;
            gemm(1, Ab + off, hd1T, head_b1, nullptr, B4, CHKR, FFf, Dd, 1, 0);
            k_head<<<CHKR, 256, 0, stream>>>(B4, head_w2, head_b2, out + b*Gg + c*CHKR);
        }
    }
}

// Round 5
// 22248.877 us; speedup vs baseline: 5.3826x; 1.4091x over previous
//
#include <hip/hip_runtime.h>

// SimplePerformer forward: bf16-MFMA GEMMs (global_load_lds, frag-ordered LDS),
// fused QKV, reg-cached FAVOR+ attention.  ~90 MB workspace.
// B=8 G=20000 D=256 H=8 DH=32 L=4 M=128 FF=1024
#define Bb 8
#define Gg 20000
#define Dd 256
#define Hh 8
#define DHh 32
#define Ll 4
#define Mm 128
#define FFf 1024
#define QKVS 768   // fused qkv row stride: [k | v | q]

typedef __attribute__((ext_vector_type(8))) short bf16x8;
typedef __attribute__((ext_vector_type(4))) float f32x4;

__device__ __forceinline__ float geluf(float x) {
    return 0.5f * x * (1.0f + erff(x * 0.70710678118654752f));
}
__device__ __forceinline__ float bf2f(ushort u) {
    union { uint i; float f; } v; v.i = ((uint)u) << 16; return v.f;
}
__device__ __forceinline__ ushort f2bf(float f) {
    union { float f; uint i; } v; v.f = f;
    uint i = v.i;
    return (ushort)((i + 0x7FFFu + ((i >> 16) & 1u)) >> 16);   // RNE
}
__device__ __forceinline__ void gload16(const void* g, void* l) {
    __builtin_amdgcn_global_load_lds(
        (const __attribute__((address_space(1))) void*)g,
        (__attribute__((address_space(3))) void*)l, 16, 0, 0);
}

// ------------------------------------------------- weight transpose-cast
// src [K,N] fp32 -> dst [N,K] bf16.  grid (N/32, K/32), block 256
__global__ __launch_bounds__(256) void k_wt(const float* __restrict__ src,
    ushort* __restrict__ dst, int K, int N)
{
    __shared__ float tl[32][33];
    const int n0 = blockIdx.x * 32, k0 = blockIdx.y * 32;
    const int tx = threadIdx.x & 31, ty = threadIdx.x >> 5;
#pragma unroll
    for (int i = 0; i < 4; i++)
        tl[ty + i*8][tx] = src[(size_t)(k0 + ty + i*8) * N + n0 + tx];
    __syncthreads();
#pragma unroll
    for (int i = 0; i < 4; i++)
        dst[(size_t)(n0 + ty + i*8) * K + k0 + tx] = f2bf(tl[tx][ty + i*8]);
}

// ------------------------------------------------- bf16 MFMA GEMM 128x128
// C = act(A@B + bias) [+res] [+C_old]; A [Mrows,K] bf16, Bt [N,K] bf16.
// grid (N/128, ceil(Mrows/128)), block 256 (4 waves, 2x2 of 64x64).
// LDS fragment-ordered: group (rg,q,lr) at shorts rg*512 + q*128 + lr*8,
// so ds_read_b128 at rg*512 + lane*8 is lane-contiguous (conflict-free) and
// global_load_lds (1KB/instr) fills exactly one rg group.
template<int CBF>
__global__ __launch_bounds__(256) void gemm_bf(
    const ushort* __restrict__ A, const ushort* __restrict__ Bt,
    const float* __restrict__ bias, const float* __restrict__ res,
    void* __restrict__ Cv, int Mrows, int N, int K, int act, int addC)
{
    __shared__ ushort As[8192];   // 16 KB
    __shared__ ushort Bs[8192];
    const int t = threadIdx.x;
    const int l = t & 63, wid = t >> 6;
    const int row0 = blockIdx.y * 128, col0 = blockIdx.x * 128;
    const int lr = l & 15, q = l >> 4;

    // staging: wave wid fills rg = wid*2 + {0,1} for both A and B
    const int ar0 = min(row0 + wid*32      + lr, Mrows - 1);
    const int ar1 = min(row0 + wid*32 + 16 + lr, Mrows - 1);
    const int br0 = col0 + wid*32      + lr;
    const int br1 = col0 + wid*32 + 16 + lr;
    const ushort* gA0 = A  + (size_t)ar0 * K + q*8;
    const ushort* gA1 = A  + (size_t)ar1 * K + q*8;
    const ushort* gB0 = Bt + (size_t)br0 * K + q*8;
    const ushort* gB1 = Bt + (size_t)br1 * K + q*8;
    ushort* lA0 = As + wid*1024;
    ushort* lA1 = As + wid*1024 + 512;
    ushort* lB0 = Bs + wid*1024;
    ushort* lB1 = Bs + wid*1024 + 512;

    const int rgA = (wid & 1) * 4;    // A rows (wid&1)*64
    const int rgB = (wid >> 1) * 4;   // B cols (wid>>1)*64

    f32x4 acc[4][4] = {};

    for (int k0 = 0; k0 < K; k0 += 32) {
        gload16(gA0 + k0, lA0);
        gload16(gA1 + k0, lA1);
        gload16(gB0 + k0, lB0);
        gload16(gB1 + k0, lB1);
        __syncthreads();              // compiler drains vmcnt(0) before barrier
        bf16x8 af[4];
#pragma unroll
        for (int mi = 0; mi < 4; mi++)
            af[mi] = *(const bf16x8*)&As[(rgA + mi)*512 + l*8];
#pragma unroll
        for (int ni = 0; ni < 4; ni++) {
            bf16x8 bfv = *(const bf16x8*)&Bs[(rgB + ni)*512 + l*8];
#pragma unroll
            for (int mi = 0; mi < 4; mi++)
                acc[mi][ni] = __builtin_amdgcn_mfma_f32_16x16x32_bf16(
                    af[mi], bfv, acc[mi][ni], 0, 0, 0);
        }
        __syncthreads();              // protect LDS from next-iter overwrite
    }

#pragma unroll
    for (int mi = 0; mi < 4; mi++) {
#pragma unroll
        for (int j = 0; j < 4; j++) {
            int row = row0 + (wid & 1)*64 + mi*16 + q*4 + j;
            if (row >= Mrows) continue;
#pragma unroll
            for (int ni = 0; ni < 4; ni++) {
                int col = col0 + (wid >> 1)*64 + ni*16 + lr;
                float v = acc[mi][ni][j];
                if (bias) v += bias[col];
                if (act == 1) v = fmaxf(v, 0.f);
                else if (act == 2) v = geluf(v);
                size_t ci = (size_t)row * N + col;
                if (res) v += res[ci];
                if (CBF) {
                    ((ushort*)Cv)[ci] = f2bf(v);
                } else {
                    float* C = (float*)Cv;
                    if (addC) v += C[ci];
                    C[ci] = v;
                }
            }
        }
    }
}

// ------------------------------------------------- small kernels
__global__ __launch_bounds__(256) void k_zero(float* __restrict__ p, int n) {
    int i = blockIdx.x*256 + threadIdx.x;
    if (i < n) p[i] = 0.f;
}

__global__ __launch_bounds__(256) void k_se1(const float* __restrict__ x,
    const float* __restrict__ w1, float* __restrict__ t1)
{
    const int blk = blockIdx.x, b = blockIdx.y, t = threadIdx.x;
    const int k0 = blk * 250;
    float acc = 0.f;
    for (int kk = 0; kk < 250; kk++) {
        float xv = x[b*Gg + k0 + kk];
        acc += xv * w1[(size_t)(k0 + kk)*256 + t];
    }
    atomicAdd(&t1[b*256 + t], acc);
}

__global__ __launch_bounds__(256) void k_se2(const float* __restrict__ t1,
    const float* __restrict__ b1, const float* __restrict__ w2,
    const float* __restrict__ b2, float* __restrict__ samp)
{
    const int b = blockIdx.x, t = threadIdx.x;
    __shared__ float s1[256];
    s1[t] = fmaxf(t1[b*256 + t] + b1[t], 0.f);
    __syncthreads();
    float acc = 0.f;
    for (int n = 0; n < 256; n++) acc += s1[n] * w2[(size_t)n*256 + t];
    samp[b*256 + t] = acc + b2[t];
}

__global__ __launch_bounds__(256) void k_embed(const float* __restrict__ x,
    const float* __restrict__ gene_emb, const float* __restrict__ samp,
    ushort* __restrict__ outb, int b)
{
    const int g = blockIdx.x;
    const int d = threadIdx.x;
    const float xv = x[b*Gg + g];
    const int j = d & 127;
    float ang = xv * expf(-(float)j * 0.035977892078032f);   // ln(100)/128
    float ree = (d < 128) ? sinf(ang) : cosf(ang);
    if (xv == -10.0f) ree = 0.f;
    outb[(size_t)g*256 + d] =
        f2bf(gene_emb[(size_t)g*256 + d] + ree + samp[b*256 + d]);
}

// LayerNorm fp32 -> bf16.  grid(rows)
__global__ __launch_bounds__(256) void k_ln(const float* __restrict__ src,
    ushort* __restrict__ dst, const float* __restrict__ gam,
    const float* __restrict__ bet)
{
    const size_t row = blockIdx.x;
    const int t = threadIdx.x;
    float v = src[row*256 + t];
    float s1 = v, s2 = v*v;
    for (int off = 32; off; off >>= 1) {
        s1 += __shfl_down(s1, off);
        s2 += __shfl_down(s2, off);
    }
    __shared__ float a1[4], a2[4];
    if ((t & 63) == 0) { a1[t >> 6] = s1; a2[t >> 6] = s2; }
    __syncthreads();
    float m1 = (a1[0]+a1[1]+a1[2]+a1[3]) * (1.f/256.f);
    float m2 = (a2[0]+a2[1]+a2[2]+a2[3]) * (1.f/256.f);
    float inv = rsqrtf(m2 - m1*m1 + 1e-5f);
    dst[row*256 + t] = f2bf((v - m1)*inv*gam[t] + bet[t]);
}

#define DN    0.4204482076268573f
#define DN2H  0.088388347648318447f   /* 0.5*dn^2 */
#define RATIO 0.08838834764831845f

// global max of dd_k (scaled).  grid (40, 8); proj row cached in regs
__global__ __launch_bounds__(256) void k_kmax(const ushort* __restrict__ qkv,
    const float* __restrict__ proj, float* __restrict__ kmaxp)
{
    const int h = blockIdx.y, blk = blockIdx.x;
    const int t = threadIdx.x;
    __shared__ float kt[64][33];
    const int m = t & 127;
    float pr[32];
#pragma unroll
    for (int d = 0; d < 32; d++) pr[d] = proj[m*32 + d] * DN;
    const int rows = Gg / 40;   // 500
    const int g0 = blk * rows;
    float mx = -1e30f;
    for (int gc = 0; gc < rows; gc += 64) {
        const int nr = min(64, rows - gc);
        __syncthreads();
        for (int i = t; i < 2048; i += 256) {
            int r = i >> 5, d = i & 31;
            kt[r][d] = (r < nr) ?
                bf2f(qkv[(size_t)(g0 + gc + r)*QKVS + h*32 + d]) : 0.f;
        }
        __syncthreads();
        const int rb = t >> 7;           // 0/1
        for (int s = 0; s < 32; s++) {
            int r = rb + 2*s;
            if (r >= nr) break;
            float sdot = 0.f;
#pragma unroll
            for (int d = 0; d < 32; d++) sdot += kt[r][d] * pr[d];
            mx = fmaxf(mx, sdot);
        }
    }
    for (int off = 32; off; off >>= 1) mx = fmaxf(mx, __shfl_down(mx, off));
    __shared__ float sm[4];
    if ((t & 63) == 0) sm[t >> 6] = mx;
    __syncthreads();
    if (t == 0) kmaxp[h*64 + blk] = fmaxf(fmaxf(sm[0], sm[1]), fmaxf(sm[2], sm[3]));
}

__global__ void k_kmax_red(const float* __restrict__ kmaxp, float* __restrict__ kmax) {
    const int t = threadIdx.x;
    if (t < 8) {
        float m = -1e30f;
        for (int i = 0; i < 40; i++) m = fmaxf(m, kmaxp[t*64 + i]);
        kmax[t] = m;
    }
}

// ctx[h,m,dh] += sum_g kp[g,m]*v[g,dh]; ksum[h,m] += sum_g kp.  grid (64, 8)
__global__ __launch_bounds__(256) void k_ctx(
    const ushort* __restrict__ qkv, const float* __restrict__ proj,
    const float* __restrict__ kmax, float* __restrict__ ctx_g,
    float* __restrict__ ksum_g)
{
    const int h = blockIdx.y, blk = blockIdx.x;
    const int t = threadIdx.x;
    __shared__ float kt[32][33];
    __shared__ float vt[32][36];
    __shared__ float kp[32][128];
    __shared__ float diag[32];
    const int m = t & 127;
    float pr[32];
#pragma unroll
    for (int d = 0; d < 32; d++) pr[d] = proj[m*32 + d] * DN;
    const float km = kmax[h];
    const int rowsA = 313;
    const int g0 = blk * rowsA;
    const int rows = min(rowsA, Gg - g0);
    float acc[16];
#pragma unroll
    for (int j = 0; j < 16; j++) acc[j] = 0.f;
    float ksl = 0.f;
    const int dh0 = (t >> 7) * 16;
    for (int gc = 0; gc < rows; gc += 32) {
        const int nr = min(32, rows - gc);
        __syncthreads();
        for (int i = t; i < 1024; i += 256) {
            int r = i >> 5, d = i & 31;
            float kv = 0.f, vv = 0.f;
            if (r < nr) {
                size_t base = (size_t)(g0 + gc + r)*QKVS + h*32 + d;
                kv = bf2f(qkv[base]); vv = bf2f(qkv[base + 256]);
            }
            kt[r][d] = kv; vt[r][d] = vv;
        }
        __syncthreads();
        if (t < 32) {
            float s = 0.f;
#pragma unroll
            for (int d = 0; d < 32; d++) s += kt[t][d]*kt[t][d];
            diag[t] = DN2H * s;
        }
        __syncthreads();
        const int rb = t >> 7;
        for (int s = 0; s < 16; s++) {
            int r = rb + 2*s;
            float val = 0.f;
            if (r < nr) {
                float sd = 0.f;
#pragma unroll
                for (int d = 0; d < 32; d++) sd += kt[r][d] * pr[d];
                val = RATIO * (expf(sd - diag[r] - km) + 1e-4f);
            }
            if (r < 32) kp[r][m] = val;
        }
        __syncthreads();
        for (int g = 0; g < nr; g++) {
            float kpv = kp[g][m];
            if (t < 128) ksl += kpv;
            const float4* vp = (const float4*)&vt[g][dh0];
            float4 v0 = vp[0], v1 = vp[1], v2 = vp[2], v3 = vp[3];
            acc[0]  += kpv*v0.x; acc[1]  += kpv*v0.y; acc[2]  += kpv*v0.z; acc[3]  += kpv*v0.w;
            acc[4]  += kpv*v1.x; acc[5]  += kpv*v1.y; acc[6]  += kpv*v1.z; acc[7]  += kpv*v1.w;
            acc[8]  += kpv*v2.x; acc[9]  += kpv*v2.y; acc[10] += kpv*v2.z; acc[11] += kpv*v2.w;
            acc[12] += kpv*v3.x; acc[13] += kpv*v3.y; acc[14] += kpv*v3.z; acc[15] += kpv*v3.w;
        }
    }
#pragma unroll
    for (int j = 0; j < 16; j++)
        atomicAdd(&ctx_g[((size_t)h*128 + m)*32 + dh0 + j], acc[j]);
    if (t < 128) atomicAdd(&ksum_g[h*128 + m], ksl);
}

// o = dinv * qp @ ctx.  grid (64, 8); 4 lanes per row; q cached in regs
__global__ __launch_bounds__(256) void k_attn(
    const ushort* __restrict__ qkv, const float* __restrict__ ctx_g,
    const float* __restrict__ ksum_g, const float* __restrict__ proj,
    ushort* __restrict__ obuf)
{
    const int h = blockIdx.y, blk = blockIdx.x;
    const int t = threadIdx.x;
    __shared__ float ps[128][32];   // swizzled: col = (d + (m>>5)*8)&31
    __shared__ float cs[128][32];
    __shared__ float ks[128];
    __shared__ float qt[64][33];
    for (int i = t; i < 4096; i += 256) {
        int mm = i >> 5, d = i & 31;
        int c = (d + (mm >> 5)*8) & 31;
        ps[mm][c] = proj[i];
        cs[mm][c] = ctx_g[(size_t)h*4096 + i];
    }
    if (t < 128) ks[t] = ksum_g[h*128 + t];
    const int rowsA = 313;
    const int g0 = blk * rowsA;
    const int rows = min(rowsA, Gg - g0);
    const int sub = t & 3, r = t >> 2;
    const int mbase = sub * 32;
    const int sub2 = sub * 2;        // float4 swizzle offset
    for (int gc = 0; gc < rows; gc += 64) {
        const int nr = min(64, rows - gc);
        __syncthreads();
        for (int i = t; i < 2048; i += 256) {
            int rr = i >> 5, d = i & 31;
            qt[rr][d] = (rr < nr) ?
                bf2f(qkv[(size_t)(g0 + gc + rr)*QKVS + 512 + h*32 + d]) : 0.f;
        }
        __syncthreads();
        float qr[32];
        float diag = 0.f;
#pragma unroll
        for (int d = 0; d < 32; d++) {
            float qv = qt[r][d] * DN;
            qr[d] = qv;
            diag += qv * qv;
        }
        diag *= 0.5f;
        float dd[32];
        float mx = -1e30f;
#pragma unroll 4
        for (int j = 0; j < 32; j++) {
            const float4* p4 = (const float4*)&ps[mbase + j][0];
            float s = 0.f;
#pragma unroll
            for (int d4 = 0; d4 < 8; d4++) {
                float4 v = p4[(d4 + sub2) & 7];
                s += qr[d4*4+0]*v.x + qr[d4*4+1]*v.y + qr[d4*4+2]*v.z + qr[d4*4+3]*v.w;
            }
            dd[j] = s;
            mx = fmaxf(mx, s);
        }
        mx = fmaxf(mx, __shfl_xor(mx, 1));
        mx = fmaxf(mx, __shfl_xor(mx, 2));
        float den = 0.f;
#pragma unroll 4
        for (int j = 0; j < 32; j++) {
            float p = RATIO * (expf(dd[j] - diag - mx) + 1e-4f);
            dd[j] = p;
            den += p * ks[mbase + j];
        }
        den += __shfl_xor(den, 1);
        den += __shfl_xor(den, 2);
        float dinv = 1.f / den;
        float oa[32];
#pragma unroll
        for (int d = 0; d < 32; d++) oa[d] = 0.f;
#pragma unroll 4
        for (int j = 0; j < 32; j++) {
            float p = dd[j];
            const float4* c4 = (const float4*)&cs[mbase + j][0];
#pragma unroll
            for (int d4 = 0; d4 < 8; d4++) {
                float4 v = c4[(d4 + sub2) & 7];
                oa[d4*4+0] += p*v.x; oa[d4*4+1] += p*v.y;
                oa[d4*4+2] += p*v.z; oa[d4*4+3] += p*v.w;
            }
        }
#pragma unroll
        for (int d = 0; d < 32; d++) {
            oa[d] += __shfl_xor(oa[d], 1);
            oa[d] += __shfl_xor(oa[d], 2);
        }
        if (r < nr) {
            size_t base = (size_t)(g0 + gc + r)*256 + h*32;
#pragma unroll
            for (int jj = 0; jj < 8; jj++)
                obuf[base + sub*8 + jj] = f2bf(dinv * oa[sub*8 + jj]);
        }
    }
}

// head layer 2: out[row] = relu(u[row,:]@w2 + b2).  16 rows/block
__global__ __launch_bounds__(256) void k_head(const ushort* __restrict__ u,
    const float* __restrict__ w2, const float* __restrict__ b2,
    float* __restrict__ outp, int nrows)
{
    const int wv = threadIdx.x >> 6, l = threadIdx.x & 63;
    const int row0 = blockIdx.x * 16 + wv * 4;
#pragma unroll
    for (int it = 0; it < 4; it++) {
        int row = row0 + it;
        if (row >= nrows) break;
        float a = 0.f;
#pragma unroll
        for (int k = 0; k < 16; k++)
            a += bf2f(u[(size_t)row*1024 + l + k*64]) * w2[l + k*64];
        for (int off = 32; off; off >>= 1) a += __shfl_down(a, off);
        if (l == 0) outp[row] = fmaxf(a + b2[0], 0.f);
    }
}

// ---------------------------------------------------------------- launch
extern "C" void kernel_launch(void* const* d_in, const int* in_sizes, int n_in,
                              void* d_out, int out_size, void* d_ws, size_t ws_size,
                              hipStream_t stream)
{
    const float* x        = (const float*)d_in[0];
    const float* gene_emb = (const float*)d_in[1];
    const float* se_w1    = (const float*)d_in[2];
    const float* se_b1    = (const float*)d_in[3];
    const float* se_w2    = (const float*)d_in[4];
    const float* se_b2    = (const float*)d_in[5];
    const float* proj_w1  = (const float*)d_in[6];
    const float* proj_b1  = (const float*)d_in[7];
    const float* proj_w2  = (const float*)d_in[8];
    const float* proj_b2  = (const float*)d_in[9];
    const float* ln1_g    = (const float*)d_in[10];
    const float* ln1_b    = (const float*)d_in[11];
    const float* wq       = (const float*)d_in[12];
    const float* wk       = (const float*)d_in[13];
    const float* wv       = (const float*)d_in[14];
    const float* wo       = (const float*)d_in[15];
    const float* bo       = (const float*)d_in[16];
    const float* ln2_g    = (const float*)d_in[17];
    const float* ln2_b    = (const float*)d_in[18];
    const float* ff_w1    = (const float*)d_in[19];
    const float* ff_b1    = (const float*)d_in[20];
    const float* ff_w2    = (const float*)d_in[21];
    const float* ff_b2    = (const float*)d_in[22];
    const float* featp    = (const float*)d_in[23];
    const float* norm_g   = (const float*)d_in[24];
    const float* norm_b   = (const float*)d_in[25];
    const float* head_w1  = (const float*)d_in[26];
    const float* head_b1  = (const float*)d_in[27];
    const float* head_w2  = (const float*)d_in[28];
    const float* head_b2  = (const float*)d_in[29];
    float* out = (float*)d_out;

    // FF chunk: 10000 rows (89.9 MB total) or 20000 (100.2 MB) if ws allows
    const int CHKF = (ws_size >= (size_t)102000000) ? 20000 : 10000;
    const int NCHF = Gg / CHKF;

    float* w = (float*)d_ws;
    const size_t SB = (size_t)Gg * Dd;          // 5,120,000
    float* f_h = w;                              // [G,D] fp32
    float* B1  = w + SB;                         // [G,D] fp32 (y)
    float* t1    = w + 2*SB;                     // 2048
    float* samp  = t1 + 2048;                    // 2048
    float* ctx   = samp + 2048;                  // 32768
    float* ksum  = ctx + 32768;                  // 1024
    float* kmaxp = ksum + 1024;                  // 512
    float* kmax  = kmaxp + 512;                  // 8
    ushort* Ab  = (ushort*)(w + 2*SB + 40000);   // [G,256] bf16
    ushort* U   = Ab + SB;                       // union: QKV [G,768] | B4 [CHKF,1024]
    const size_t usz = (size_t)Gg * QKVS > (size_t)CHKF * FFf
                     ? (size_t)Gg * QKVS : (size_t)CHKF * FFf;
    ushort* Wt  = U + usz;                       // 3,932,160 bf16
    ushort* QKVb = U;
    ushort* B4   = U;

    auto gemm = [&](int CBF, const ushort* A, const ushort* Bw,
                    const float* bias, const float* res, void* C,
                    int Mr, int N, int K, int act, int addC) {
        dim3 grid(N/128, (Mr + 127)/128);
        if (CBF) gemm_bf<1><<<grid, 256, 0, stream>>>(A, Bw, bias, res, C, Mr, N, K, act, addC);
        else     gemm_bf<0><<<grid, 256, 0, stream>>>(A, Bw, bias, res, C, Mr, N, K, act, addC);
    };
    auto castw = [&](const float* src, ushort* dst, int K, int N) {
        k_wt<<<dim3(N/32, K/32), 256, 0, stream>>>(src, dst, K, N);
    };

    // ---------------- weight casts: per layer [k|v|q][256] + wo + ff1 + ff2
    const size_t LW = 786432;
    for (int l = 0; l < Ll; l++) {
        ushort* lw = Wt + (size_t)l * LW;
        castw(wk + (size_t)l*65536,     lw,          256, 256);
        castw(wv + (size_t)l*65536,     lw + 65536,  256, 256);
        castw(wq + (size_t)l*65536,     lw + 131072, 256, 256);
        castw(wo + (size_t)l*65536,     lw + 196608, 256, 256);
        castw(ff_w1 + (size_t)l*262144, lw + 262144, 256, 1024);
        castw(ff_w2 + (size_t)l*262144, lw + 524288, 1024, 256);
    }
    ushort* pj1T = Wt + 4*LW;
    ushort* pj2T = pj1T + 262144;
    ushort* hd1T = pj2T + 262144;
    castw(proj_w1, pj1T, 256, 1024);
    castw(proj_w2, pj2T, 1024, 256);
    castw(head_w1, hd1T, 256, 1024);

    // ---------------- sample embedding (all batches)
    k_zero<<<8, 256, 0, stream>>>(t1, 2048);
    k_se1<<<dim3(80, 8), 256, 0, stream>>>(x, se_w1, t1);
    k_se2<<<8, 256, 0, stream>>>(t1, se_b1, se_w2, se_b2, samp);

    // ---------------- per batch full network
    for (int b = 0; b < Bb; b++) {
        k_embed<<<Gg, 256, 0, stream>>>(x, gene_emb, samp, Ab, b);
        for (int c = 0; c < NCHF; c++) {
            size_t off = (size_t)c * CHKF * Dd;
            gemm(1, Ab + off, pj1T, proj_b1, nullptr, B4, CHKF, FFf, Dd, 1, 0);
            gemm(0, B4, pj2T, proj_b2, nullptr, f_h + off, CHKF, Dd, FFf, 0, 0);
        }
        for (int l = 0; l < Ll; l++) {
            ushort* lw = Wt + (size_t)l * LW;
            const ushort* qkvT = lw;
            const ushort* oT   = lw + 196608;
            const ushort* f1T  = lw + 262144;
            const ushort* f2T  = lw + 524288;
            const float* pproj = featp + (size_t)l*Mm*DHh;

            k_ln<<<Gg, 256, 0, stream>>>(f_h, Ab, ln1_g + l*Dd, ln1_b + l*Dd);
            gemm(1, Ab, qkvT, nullptr, nullptr, QKVb, Gg, QKVS, Dd, 0, 0);
            k_kmax<<<dim3(40, 8), 256, 0, stream>>>(QKVb, pproj, kmaxp);
            k_kmax_red<<<1, 64, 0, stream>>>(kmaxp, kmax);
            k_zero<<<132, 256, 0, stream>>>(ctx, 32768 + 1024);
            k_ctx<<<dim3(64, 8), 256, 0, stream>>>(QKVb, pproj, kmax, ctx, ksum);
            k_attn<<<dim3(64, 8), 256, 0, stream>>>(QKVb, ctx, ksum, pproj, Ab);
            gemm(0, Ab, oT, bo + l*Dd, f_h, B1, Gg, Dd, Dd, 0, 0);        // y fp32
            k_ln<<<Gg, 256, 0, stream>>>(B1, Ab, ln2_g + l*Dd, ln2_b + l*Dd);
            for (int c = 0; c < NCHF; c++) {
                size_t off = (size_t)c * CHKF * Dd;
                gemm(1, Ab + off, f1T, ff_b1 + l*FFf, nullptr, B4, CHKF, FFf, Dd, 2, 0);
                gemm(0, B4, f2T, ff_b2 + l*Dd, B1 + off, f_h + off, CHKF, Dd, FFf, 0, 1);
            }
        }
        k_ln<<<Gg, 256, 0, stream>>>(f_h, Ab, norm_g, norm_b);
        for (int c = 0; c < NCHF; c++) {
            size_t off = (size_t)c * CHKF * Dd;
            gemm(1, Ab + off, hd1T, head_b1, nullptr, B4, CHKF, FFf, Dd, 1, 0);
            k_head<<<(CHKF + 15)/16, 256, 0, stream>>>(B4, head_w2, head_b2,
                                                       out + b*Gg + c*CHKF, CHKF);
        }
    }
}

// Round 6
// 11533.476 us; speedup vs baseline: 10.3833x; 1.9291x over previous
//
#include <hip/hip_runtime.h>

// SimplePerformer forward: bf16-MFMA GEMMs + MFMA FAVOR+ attention.
// B=8 G=20000 D=256 H=8 DH=32 L=4 M=128 FF=1024
#define Bb 8
#define Gg 20000
#define Dd 256
#define Hh 8
#define DHh 32
#define Ll 4
#define Mm 128
#define FFf 1024
#define QKVS 768   // fused qkv row stride: [k | v | q]
#define NBLK 313   // rows per attention block (64 blocks)

typedef __attribute__((ext_vector_type(8))) short bf16x8;
typedef __attribute__((ext_vector_type(4))) float f32x4;

#define DN    0.4204482076268573f     /* 32^-0.25 */
#define DN2H  0.088388347648318447f   /* 0.5 * 32^-0.5 */
#define RATIO 0.08838834764831845f    /* 128^-0.5 */
#define EPSK  1e-4f

__device__ __forceinline__ float geluf(float x) {
    return 0.5f * x * (1.0f + erff(x * 0.70710678118654752f));
}
__device__ __forceinline__ float bf2f(ushort u) {
    union { uint i; float f; } v; v.i = ((uint)u) << 16; return v.f;
}
__device__ __forceinline__ ushort f2bf(float f) {
    union { float f; uint i; } v; v.f = f;
    uint i = v.i;
    return (ushort)((i + 0x7FFFu + ((i >> 16) & 1u)) >> 16);   // RNE
}
__device__ __forceinline__ void gload16(const void* g, void* l) {
    __builtin_amdgcn_global_load_lds(
        (const __attribute__((address_space(1))) void*)g,
        (__attribute__((address_space(3))) void*)l, 16, 0, 0);
}

// ------------------------------------------------- weight transpose-cast
__global__ __launch_bounds__(256) void k_wt(const float* __restrict__ src,
    ushort* __restrict__ dst, int K, int N)
{
    __shared__ float tl[32][33];
    const int n0 = blockIdx.x * 32, k0 = blockIdx.y * 32;
    const int tx = threadIdx.x & 31, ty = threadIdx.x >> 5;
#pragma unroll
    for (int i = 0; i < 4; i++)
        tl[ty + i*8][tx] = src[(size_t)(k0 + ty + i*8) * N + n0 + tx];
    __syncthreads();
#pragma unroll
    for (int i = 0; i < 4; i++)
        dst[(size_t)(n0 + ty + i*8) * K + k0 + tx] = f2bf(tl[tx][ty + i*8]);
}

// straight cast fp32 -> bf16
__global__ __launch_bounds__(256) void k_pcast(const float* __restrict__ src,
    ushort* __restrict__ dst, int n)
{
    int i = blockIdx.x*256 + threadIdx.x;
    if (i < n) dst[i] = f2bf(src[i]);
}

// ------------------------------------------------- bf16 MFMA GEMM 128x128
template<int CBF>
__global__ __launch_bounds__(256) void gemm_bf(
    const ushort* __restrict__ A, const ushort* __restrict__ Bt,
    const float* __restrict__ bias, const float* __restrict__ res,
    void* __restrict__ Cv, int Mrows, int N, int K, int act, int addC)
{
    __shared__ ushort As[8192];
    __shared__ ushort Bs[8192];
    const int t = threadIdx.x;
    const int l = t & 63, wid = t >> 6;
    const int row0 = blockIdx.y * 128, col0 = blockIdx.x * 128;
    const int lr = l & 15, q = l >> 4;

    const int ar0 = min(row0 + wid*32      + lr, Mrows - 1);
    const int ar1 = min(row0 + wid*32 + 16 + lr, Mrows - 1);
    const int br0 = col0 + wid*32      + lr;
    const int br1 = col0 + wid*32 + 16 + lr;
    const ushort* gA0 = A  + (size_t)ar0 * K + q*8;
    const ushort* gA1 = A  + (size_t)ar1 * K + q*8;
    const ushort* gB0 = Bt + (size_t)br0 * K + q*8;
    const ushort* gB1 = Bt + (size_t)br1 * K + q*8;
    ushort* lA0 = As + wid*1024;
    ushort* lA1 = As + wid*1024 + 512;
    ushort* lB0 = Bs + wid*1024;
    ushort* lB1 = Bs + wid*1024 + 512;

    const int rgA = (wid & 1) * 4;
    const int rgB = (wid >> 1) * 4;

    f32x4 acc[4][4] = {};

    for (int k0 = 0; k0 < K; k0 += 32) {
        gload16(gA0 + k0, lA0);
        gload16(gA1 + k0, lA1);
        gload16(gB0 + k0, lB0);
        gload16(gB1 + k0, lB1);
        __syncthreads();
        bf16x8 af[4];
#pragma unroll
        for (int mi = 0; mi < 4; mi++)
            af[mi] = *(const bf16x8*)&As[(rgA + mi)*512 + l*8];
#pragma unroll
        for (int ni = 0; ni < 4; ni++) {
            bf16x8 bfv = *(const bf16x8*)&Bs[(rgB + ni)*512 + l*8];
#pragma unroll
            for (int mi = 0; mi < 4; mi++)
                acc[mi][ni] = __builtin_amdgcn_mfma_f32_16x16x32_bf16(
                    af[mi], bfv, acc[mi][ni], 0, 0, 0);
        }
        __syncthreads();
    }

#pragma unroll
    for (int mi = 0; mi < 4; mi++) {
#pragma unroll
        for (int j = 0; j < 4; j++) {
            int row = row0 + (wid & 1)*64 + mi*16 + q*4 + j;
            if (row >= Mrows) continue;
#pragma unroll
            for (int ni = 0; ni < 4; ni++) {
                int col = col0 + (wid >> 1)*64 + ni*16 + lr;
                float v = acc[mi][ni][j];
                if (bias) v += bias[col];
                if (act == 1) v = fmaxf(v, 0.f);
                else if (act == 2) v = geluf(v);
                size_t ci = (size_t)row * N + col;
                if (res) v += res[ci];
                if (CBF) {
                    ((ushort*)Cv)[ci] = f2bf(v);
                } else {
                    float* C = (float*)Cv;
                    if (addC) v += C[ci];
                    C[ci] = v;
                }
            }
        }
    }
}

// ------------------------------------------------- small kernels
__global__ __launch_bounds__(256) void k_zero(float* __restrict__ p, int n) {
    int i = blockIdx.x*256 + threadIdx.x;
    if (i < n) p[i] = 0.f;
}

__global__ __launch_bounds__(256) void k_se1(const float* __restrict__ x,
    const float* __restrict__ w1, float* __restrict__ t1)
{
    const int blk = blockIdx.x, b = blockIdx.y, t = threadIdx.x;
    const int k0 = blk * 250;
    float acc = 0.f;
    for (int kk = 0; kk < 250; kk++) {
        float xv = x[b*Gg + k0 + kk];
        acc += xv * w1[(size_t)(k0 + kk)*256 + t];
    }
    atomicAdd(&t1[b*256 + t], acc);
}

__global__ __launch_bounds__(256) void k_se2(const float* __restrict__ t1,
    const float* __restrict__ b1, const float* __restrict__ w2,
    const float* __restrict__ b2, float* __restrict__ samp)
{
    const int b = blockIdx.x, t = threadIdx.x;
    __shared__ float s1[256];
    s1[t] = fmaxf(t1[b*256 + t] + b1[t], 0.f);
    __syncthreads();
    float acc = 0.f;
    for (int n = 0; n < 256; n++) acc += s1[n] * w2[(size_t)n*256 + t];
    samp[b*256 + t] = acc + b2[t];
}

__global__ __launch_bounds__(256) void k_embed(const float* __restrict__ x,
    const float* __restrict__ gene_emb, const float* __restrict__ samp,
    ushort* __restrict__ outb, int b)
{
    const int g = blockIdx.x;
    const int d = threadIdx.x;
    const float xv = x[b*Gg + g];
    const int j = d & 127;
    float ang = xv * expf(-(float)j * 0.035977892078032f);   // ln(100)/128
    float ree = (d < 128) ? sinf(ang) : cosf(ang);
    if (xv == -10.0f) ree = 0.f;
    outb[(size_t)g*256 + d] =
        f2bf(gene_emb[(size_t)g*256 + d] + ree + samp[b*256 + d]);
}

__global__ __launch_bounds__(256) void k_ln(const float* __restrict__ src,
    ushort* __restrict__ dst, const float* __restrict__ gam,
    const float* __restrict__ bet)
{
    const size_t row = blockIdx.x;
    const int t = threadIdx.x;
    float v = src[row*256 + t];
    float s1 = v, s2 = v*v;
    for (int off = 32; off; off >>= 1) {
        s1 += __shfl_down(s1, off);
        s2 += __shfl_down(s2, off);
    }
    __shared__ float a1[4], a2[4];
    if ((t & 63) == 0) { a1[t >> 6] = s1; a2[t >> 6] = s2; }
    __syncthreads();
    float m1 = (a1[0]+a1[1]+a1[2]+a1[3]) * (1.f/256.f);
    float m2 = (a2[0]+a2[1]+a2[2]+a2[3]) * (1.f/256.f);
    float inv = rsqrtf(m2 - m1*m1 + 1e-5f);
    dst[row*256 + t] = f2bf((v - m1)*inv*gam[t] + bet[t]);
}

// ------------------------------------------------- MFMA FAVOR+ attention
// kmax partials + zero ctxT/ksum.  grid (64, 8)
__global__ __launch_bounds__(256) void k_kmax(const ushort* __restrict__ qkv,
    const ushort* __restrict__ projb, float* __restrict__ kmaxp,
    float* __restrict__ ctxT, float* __restrict__ ksum)
{
    const int h = blockIdx.y, blk = blockIdx.x;
    const int t = threadIdx.x;
    const int w = t >> 6, l = t & 63;
    const int lr = l & 15, lq = l >> 4;
    if (t < 64) ctxT[(size_t)h*4096 + blk*64 + t] = 0.f;
    else if (t < 66) ksum[h*128 + blk*2 + (t - 64)] = 0.f;
    bf16x8 pb[8];
#pragma unroll
    for (int nt = 0; nt < 8; nt++)
        pb[nt] = *(const bf16x8*)(projb + (nt*16 + lr)*32 + lq*8);
    const int g0 = blk * NBLK;
    const int rows = min(NBLK, Gg - g0);
    float mx = -1e30f;
    for (int gc = 0; gc < rows; gc += 64) {
        int row = min(g0 + gc + w*16 + lr, Gg - 1);
        bf16x8 af = *(const bf16x8*)(qkv + (size_t)row*QKVS + h*32 + lq*8);
        f32x4 z = {};
#pragma unroll
        for (int nt = 0; nt < 8; nt++) {
            f32x4 dd = __builtin_amdgcn_mfma_f32_16x16x32_bf16(af, pb[nt], z, 0, 0, 0);
            mx = fmaxf(mx, fmaxf(fmaxf(dd[0], dd[1]), fmaxf(dd[2], dd[3])));
        }
    }
#pragma unroll
    for (int off = 32; off; off >>= 1) mx = fmaxf(mx, __shfl_xor(mx, off));
    __shared__ float sm[4];
    if (l == 0) sm[w] = mx;
    __syncthreads();
    if (t == 0)
        kmaxp[h*64 + blk] = fmaxf(fmaxf(sm[0], sm[1]), fmaxf(sm[2], sm[3]));
}

// ctxT[h][dh][m] += kp^T@V ; ksum[h][m] += sum kp.  grid (64, 8)
__global__ __launch_bounds__(256) void k_ctx(const ushort* __restrict__ qkv,
    const ushort* __restrict__ projb, const float* __restrict__ kmaxp,
    float* __restrict__ ctxT, float* __restrict__ ksum)
{
    __shared__ ushort kpsT[128][72];   // [m][g] bf16
    __shared__ ushort vt[32][72];      // [dh][g] bf16
    __shared__ float diag[64];
    const int h = blockIdx.y, blk = blockIdx.x;
    const int t = threadIdx.x;
    const int w = t >> 6, l = t & 63;
    const int lr = l & 15, lq = l >> 4;
    bf16x8 pb[8];
#pragma unroll
    for (int nt = 0; nt < 8; nt++)
        pb[nt] = *(const bf16x8*)(projb + (nt*16 + lr)*32 + lq*8);
    float kmr = kmaxp[h*64 + l];
#pragma unroll
    for (int off = 32; off; off >>= 1) kmr = fmaxf(kmr, __shfl_xor(kmr, off));
    const float km = kmr * DN;
    const int g0 = blk * NBLK;
    const int rows = min(NBLK, Gg - g0);
    f32x4 cacc[2][2] = {};   // [dh-tile][nt-pair]
    float ksacc[8] = {};
    for (int gc = 0; gc < rows; gc += 64) {
        const int nr = min(64, rows - gc);
        const int rbase = g0 + gc;
        int arow = min(rbase + w*16 + lr, Gg - 1);
        bf16x8 af = *(const bf16x8*)(qkv + (size_t)arow*QKVS + h*32 + lq*8);
        float s = 0.f;
#pragma unroll
        for (int j = 0; j < 8; j++) { float kv = bf2f((ushort)af[j]); s += kv*kv; }
        s += __shfl_xor(s, 16); s += __shfl_xor(s, 32);
        if (l < 16) diag[w*16 + l] = DN2H * s;
        f32x4 z = {};
        f32x4 dd[8];
#pragma unroll
        for (int nt = 0; nt < 8; nt++)
            dd[nt] = __builtin_amdgcn_mfma_f32_16x16x32_bf16(af, pb[nt], z, 0, 0, 0);
        __syncthreads();   // diag ready; prev-chunk ctx reads done
        float dg[4];
#pragma unroll
        for (int j = 0; j < 4; j++) dg[j] = diag[w*16 + lq*4 + j];
#pragma unroll
        for (int nt = 0; nt < 8; nt++) {
#pragma unroll
            for (int j = 0; j < 4; j++) {
                int rj = w*16 + lq*4 + j;
                float kp = 0.f;
                if (rj < nr) kp = RATIO * (expf(DN*dd[nt][j] - dg[j] - km) + EPSK);
                ksacc[nt] += kp;
                kpsT[nt*16 + lr][rj] = f2bf(kp);
            }
        }
        for (int i = t; i < 512; i += 256) {
            int r = i >> 3, c4 = (i & 7) * 4;
            int vrow = min(rbase + r, Gg - 1);
            const ushort* vp = qkv + (size_t)vrow*QKVS + 256 + h*32 + c4;
            vt[c4+0][r] = vp[0]; vt[c4+1][r] = vp[1];
            vt[c4+2][r] = vp[2]; vt[c4+3][r] = vp[3];
        }
        __syncthreads();   // kpsT + vt ready
#pragma unroll
        for (int ks = 0; ks < 2; ks++) {
            bf16x8 a0 = *(const bf16x8*)&vt[lr][ks*32 + lq*8];
            bf16x8 a1 = *(const bf16x8*)&vt[16 + lr][ks*32 + lq*8];
#pragma unroll
            for (int ntp = 0; ntp < 2; ntp++) {
                bf16x8 bfr = *(const bf16x8*)&kpsT[(w*2 + ntp)*16 + lr][ks*32 + lq*8];
                cacc[0][ntp] = __builtin_amdgcn_mfma_f32_16x16x32_bf16(a0, bfr, cacc[0][ntp], 0, 0, 0);
                cacc[1][ntp] = __builtin_amdgcn_mfma_f32_16x16x32_bf16(a1, bfr, cacc[1][ntp], 0, 0, 0);
            }
        }
    }
#pragma unroll
    for (int dt = 0; dt < 2; dt++)
#pragma unroll
        for (int ntp = 0; ntp < 2; ntp++)
#pragma unroll
            for (int j = 0; j < 4; j++)
                atomicAdd(&ctxT[(size_t)h*4096 + (dt*16 + lq*4 + j)*128
                                + (w*2 + ntp)*16 + lr], cacc[dt][ntp][j]);
#pragma unroll
    for (int nt = 0; nt < 8; nt++) {
        float v = ksacc[nt];
        v += __shfl_down(v, 32);
        v += __shfl_down(v, 16);
        if (l < 16) atomicAdd(&ksum[h*128 + nt*16 + l], v);
    }
}

// o = dinv * (qp @ ctx).  grid (64, 8)
__global__ __launch_bounds__(256) void k_attn(const ushort* __restrict__ qkv,
    const ushort* __restrict__ projb, const float* __restrict__ ctxT,
    const float* __restrict__ ksum, ushort* __restrict__ obuf)
{
    __shared__ ushort qps[64][136];    // [g][m] bf16
    __shared__ ushort ctxb[32][136];   // [dh][m] bf16
    __shared__ float ksl[128];
    __shared__ float dgq[64];
    const int h = blockIdx.y, blk = blockIdx.x;
    const int t = threadIdx.x;
    const int w = t >> 6, l = t & 63;
    const int lr = l & 15, lq = l >> 4;
    bf16x8 pb[8];
#pragma unroll
    for (int nt = 0; nt < 8; nt++)
        pb[nt] = *(const bf16x8*)(projb + (nt*16 + lr)*32 + lq*8);
    for (int i = t; i < 4096; i += 256)
        ctxb[i >> 7][i & 127] = f2bf(ctxT[(size_t)h*4096 + i]);
    if (t < 128) ksl[t] = ksum[h*128 + t];
    __syncthreads();
    bf16x8 cb[2][4];
#pragma unroll
    for (int dt = 0; dt < 2; dt++)
#pragma unroll
        for (int ks = 0; ks < 4; ks++)
            cb[dt][ks] = *(const bf16x8*)&ctxb[dt*16 + lr][ks*32 + lq*8];
    const int g0 = blk * NBLK;
    const int rows = min(NBLK, Gg - g0);
    for (int gc = 0; gc < rows; gc += 64) {
        const int nr = min(64, rows - gc);
        const int rbase = g0 + gc;
        int arow = min(rbase + w*16 + lr, Gg - 1);
        bf16x8 af = *(const bf16x8*)(qkv + (size_t)arow*QKVS + 512 + h*32 + lq*8);
        float s = 0.f;
#pragma unroll
        for (int j = 0; j < 8; j++) { float qv = bf2f((ushort)af[j]); s += qv*qv; }
        s += __shfl_xor(s, 16); s += __shfl_xor(s, 32);
        if (l < 16) dgq[w*16 + l] = DN2H * s;
        f32x4 z = {};
        f32x4 dd[8];
#pragma unroll
        for (int nt = 0; nt < 8; nt++)
            dd[nt] = __builtin_amdgcn_mfma_f32_16x16x32_bf16(af, pb[nt], z, 0, 0, 0);
        __syncthreads();   // dgq ready; prev-chunk qps reads done
        float dg[4], mq[4], den[4], dinv[4];
#pragma unroll
        for (int j = 0; j < 4; j++) {
            dg[j] = dgq[w*16 + lq*4 + j];
            float m = -1e30f;
#pragma unroll
            for (int nt = 0; nt < 8; nt++) m = fmaxf(m, dd[nt][j]);
            mq[j] = m;
        }
#pragma unroll
        for (int off = 1; off < 16; off <<= 1)
#pragma unroll
            for (int j = 0; j < 4; j++) mq[j] = fmaxf(mq[j], __shfl_xor(mq[j], off));
#pragma unroll
        for (int j = 0; j < 4; j++) { mq[j] = DN*mq[j]; den[j] = 0.f; }
#pragma unroll
        for (int nt = 0; nt < 8; nt++) {
            float kv = ksl[nt*16 + lr];
#pragma unroll
            for (int j = 0; j < 4; j++) {
                float p = RATIO * (expf(DN*dd[nt][j] - dg[j] - mq[j]) + EPSK);
                dd[nt][j] = p;
                den[j] += p * kv;
            }
        }
#pragma unroll
        for (int off = 1; off < 16; off <<= 1)
#pragma unroll
            for (int j = 0; j < 4; j++) den[j] += __shfl_xor(den[j], off);
#pragma unroll
        for (int j = 0; j < 4; j++) dinv[j] = 1.f / den[j];
#pragma unroll
        for (int nt = 0; nt < 8; nt++)
#pragma unroll
            for (int j = 0; j < 4; j++)
                qps[w*16 + lq*4 + j][nt*16 + lr] = f2bf(dd[nt][j]);
        __syncthreads();   // qps ready
        f32x4 oacc[2] = {};
#pragma unroll
        for (int ks = 0; ks < 4; ks++) {
            bf16x8 aq = *(const bf16x8*)&qps[w*16 + lr][ks*32 + lq*8];
            oacc[0] = __builtin_amdgcn_mfma_f32_16x16x32_bf16(aq, cb[0][ks], oacc[0], 0, 0, 0);
            oacc[1] = __builtin_amdgcn_mfma_f32_16x16x32_bf16(aq, cb[1][ks], oacc[1], 0, 0, 0);
        }
#pragma unroll
        for (int dt = 0; dt < 2; dt++)
#pragma unroll
            for (int j = 0; j < 4; j++) {
                int rj = w*16 + lq*4 + j;
                if (rj < nr)
                    obuf[(size_t)(rbase + rj)*256 + h*32 + dt*16 + lr]
                        = f2bf(oacc[dt][j] * dinv[j]);
            }
    }
}

// head layer 2.  16 rows/block
__global__ __launch_bounds__(256) void k_head(const ushort* __restrict__ u,
    const float* __restrict__ w2, const float* __restrict__ b2,
    float* __restrict__ outp, int nrows)
{
    const int wv = threadIdx.x >> 6, l = threadIdx.x & 63;
    const int row0 = blockIdx.x * 16 + wv * 4;
#pragma unroll
    for (int it = 0; it < 4; it++) {
        int row = row0 + it;
        if (row >= nrows) break;
        float a = 0.f;
#pragma unroll
        for (int k = 0; k < 16; k++)
            a += bf2f(u[(size_t)row*1024 + l + k*64]) * w2[l + k*64];
        for (int off = 32; off; off >>= 1) a += __shfl_down(a, off);
        if (l == 0) outp[row] = fmaxf(a + b2[0], 0.f);
    }
}

// ---------------------------------------------------------------- launch
extern "C" void kernel_launch(void* const* d_in, const int* in_sizes, int n_in,
                              void* d_out, int out_size, void* d_ws, size_t ws_size,
                              hipStream_t stream)
{
    const float* x        = (const float*)d_in[0];
    const float* gene_emb = (const float*)d_in[1];
    const float* se_w1    = (const float*)d_in[2];
    const float* se_b1    = (const float*)d_in[3];
    const float* se_w2    = (const float*)d_in[4];
    const float* se_b2    = (const float*)d_in[5];
    const float* proj_w1  = (const float*)d_in[6];
    const float* proj_b1  = (const float*)d_in[7];
    const float* proj_w2  = (const float*)d_in[8];
    const float* proj_b2  = (const float*)d_in[9];
    const float* ln1_g    = (const float*)d_in[10];
    const float* ln1_b    = (const float*)d_in[11];
    const float* wq       = (const float*)d_in[12];
    const float* wk       = (const float*)d_in[13];
    const float* wv       = (const float*)d_in[14];
    const float* wo       = (const float*)d_in[15];
    const float* bo       = (const float*)d_in[16];
    const float* ln2_g    = (const float*)d_in[17];
    const float* ln2_b    = (const float*)d_in[18];
    const float* ff_w1    = (const float*)d_in[19];
    const float* ff_b1    = (const float*)d_in[20];
    const float* ff_w2    = (const float*)d_in[21];
    const float* ff_b2    = (const float*)d_in[22];
    const float* featp    = (const float*)d_in[23];
    const float* norm_g   = (const float*)d_in[24];
    const float* norm_b   = (const float*)d_in[25];
    const float* head_w1  = (const float*)d_in[26];
    const float* head_b1  = (const float*)d_in[27];
    const float* head_w2  = (const float*)d_in[28];
    const float* head_b2  = (const float*)d_in[29];
    float* out = (float*)d_out;

    const int CHKF = (ws_size >= (size_t)102000000) ? 20000 : 10000;
    const int NCHF = Gg / CHKF;

    float* w = (float*)d_ws;
    const size_t SB = (size_t)Gg * Dd;
    float* f_h = w;                              // [G,D] fp32
    float* B1  = w + SB;                         // [G,D] fp32 (y)
    float* t1    = w + 2*SB;                     // 2048
    float* samp  = t1 + 2048;                    // 2048
    float* ctx   = samp + 2048;                  // 32768 (ctx^T [h][dh][m])
    float* ksum  = ctx + 32768;                  // 1024
    float* kmaxp = ksum + 1024;                  // 512
    ushort* Ab  = (ushort*)(w + 2*SB + 40000);   // [G,256] bf16
    ushort* U   = Ab + SB;                       // QKV [G,768] | B4 [CHKF,1024]
    const size_t usz = (size_t)Gg * QKVS > (size_t)CHKF * FFf
                     ? (size_t)Gg * QKVS : (size_t)CHKF * FFf;
    ushort* Wt  = U + usz;                       // 3,932,160 bf16
    ushort* projb = Wt + 3932160;                // 16384 bf16
    ushort* QKVb = U;
    ushort* B4   = U;

    auto gemm = [&](int CBF, const ushort* A, const ushort* Bw,
                    const float* bias, const float* res, void* C,
                    int Mr, int N, int K, int act, int addC) {
        dim3 grid(N/128, (Mr + 127)/128);
        if (CBF) gemm_bf<1><<<grid, 256, 0, stream>>>(A, Bw, bias, res, C, Mr, N, K, act, addC);
        else     gemm_bf<0><<<grid, 256, 0, stream>>>(A, Bw, bias, res, C, Mr, N, K, act, addC);
    };
    auto castw = [&](const float* src, ushort* dst, int K, int N) {
        k_wt<<<dim3(N/32, K/32), 256, 0, stream>>>(src, dst, K, N);
    };

    const size_t LW = 786432;
    for (int l = 0; l < Ll; l++) {
        ushort* lw = Wt + (size_t)l * LW;
        castw(wk + (size_t)l*65536,     lw,          256, 256);
        castw(wv + (size_t)l*65536,     lw + 65536,  256, 256);
        castw(wq + (size_t)l*65536,     lw + 131072, 256, 256);
        castw(wo + (size_t)l*65536,     lw + 196608, 256, 256);
        castw(ff_w1 + (size_t)l*262144, lw + 262144, 256, 1024);
        castw(ff_w2 + (size_t)l*262144, lw + 524288, 1024, 256);
    }
    ushort* pj1T = Wt + 4*LW;
    ushort* pj2T = pj1T + 262144;
    ushort* hd1T = pj2T + 262144;
    castw(proj_w1, pj1T, 256, 1024);
    castw(proj_w2, pj2T, 1024, 256);
    castw(head_w1, hd1T, 256, 1024);
    k_pcast<<<64, 256, 0, stream>>>(featp, projb, Ll*Mm*DHh);

    k_zero<<<8, 256, 0, stream>>>(t1, 2048);
    k_se1<<<dim3(80, 8), 256, 0, stream>>>(x, se_w1, t1);
    k_se2<<<8, 256, 0, stream>>>(t1, se_b1, se_w2, se_b2, samp);

    for (int b = 0; b < Bb; b++) {
        k_embed<<<Gg, 256, 0, stream>>>(x, gene_emb, samp, Ab, b);
        for (int c = 0; c < NCHF; c++) {
            size_t off = (size_t)c * CHKF * Dd;
            gemm(1, Ab + off, pj1T, proj_b1, nullptr, B4, CHKF, FFf, Dd, 1, 0);
            gemm(0, B4, pj2T, proj_b2, nullptr, f_h + off, CHKF, Dd, FFf, 0, 0);
        }
        for (int l = 0; l < Ll; l++) {
            ushort* lw = Wt + (size_t)l * LW;
            const ushort* qkvT = lw;
            const ushort* oT   = lw + 196608;
            const ushort* f1T  = lw + 262144;
            const ushort* f2T  = lw + 524288;
            const ushort* pjb  = projb + (size_t)l*Mm*DHh;

            k_ln<<<Gg, 256, 0, stream>>>(f_h, Ab, ln1_g + l*Dd, ln1_b + l*Dd);
            gemm(1, Ab, qkvT, nullptr, nullptr, QKVb, Gg, QKVS, Dd, 0, 0);
            k_kmax<<<dim3(64, 8), 256, 0, stream>>>(QKVb, pjb, kmaxp, ctx, ksum);
            k_ctx<<<dim3(64, 8), 256, 0, stream>>>(QKVb, pjb, kmaxp, ctx, ksum);
            k_attn<<<dim3(64, 8), 256, 0, stream>>>(QKVb, pjb, ctx, ksum, Ab);
            gemm(0, Ab, oT, bo + l*Dd, f_h, B1, Gg, Dd, Dd, 0, 0);
            k_ln<<<Gg, 256, 0, stream>>>(B1, Ab, ln2_g + l*Dd, ln2_b + l*Dd);
            for (int c = 0; c < NCHF; c++) {
                size_t off = (size_t)c * CHKF * Dd;
                gemm(1, Ab + off, f1T, ff_b1 + l*FFf, nullptr, B4, CHKF, FFf, Dd, 2, 0);
                gemm(0, B4, f2T, ff_b2 + l*Dd, B1 + off, f_h + off, CHKF, Dd, FFf, 0, 1);
            }
        }
        k_ln<<<Gg, 256, 0, stream>>>(f_h, Ab, norm_g, norm_b);
        for (int c = 0; c < NCHF; c++) {
            size_t off = (size_t)c * CHKF * Dd;
            gemm(1, Ab + off, hd1T, head_b1, nullptr, B4, CHKF, FFf, Dd, 1, 0);
            k_head<<<(CHKF + 15)/16, 256, 0, stream>>>(B4, head_w2, head_b2,
                                                       out + b*Gg + c*CHKF, CHKF);
        }
    }
}

// Round 7
// 11078.809 us; speedup vs baseline: 10.8094x; 1.0410x over previous
//
#include <hip/hip_runtime.h>

// SimplePerformer forward: bf16-MFMA GEMMs + MFMA FAVOR+ attention (slotted ctx).
// B=8 G=20000 D=256 H=8 DH=32 L=4 M=128 FF=1024
#define Bb 8
#define Gg 20000
#define Dd 256
#define Hh 8
#define DHh 32
#define Ll 4
#define Mm 128
#define FFf 1024
#define QKVS 768   // fused qkv row stride: [k | v | q]
#define NBLK 157   // rows per attention block (128 blocks per head)

typedef __attribute__((ext_vector_type(8))) short bf16x8;
typedef __attribute__((ext_vector_type(4))) float f32x4;

#define DN    0.4204482076268573f     /* 32^-0.25 */
#define DN2H  0.088388347648318447f   /* 0.5 * 32^-0.5 */
#define RATIO 0.08838834764831845f    /* 128^-0.5 */
#define EPSK  1e-4f

__device__ __forceinline__ float geluf(float x) {
    return 0.5f * x * (1.0f + erff(x * 0.70710678118654752f));
}
__device__ __forceinline__ float bf2f(ushort u) {
    union { uint i; float f; } v; v.i = ((uint)u) << 16; return v.f;
}
__device__ __forceinline__ ushort f2bf(float f) {
    union { float f; uint i; } v; v.f = f;
    uint i = v.i;
    return (ushort)((i + 0x7FFFu + ((i >> 16) & 1u)) >> 16);   // RNE
}
__device__ __forceinline__ void gload16(const void* g, void* l) {
    __builtin_amdgcn_global_load_lds(
        (const __attribute__((address_space(1))) void*)g,
        (__attribute__((address_space(3))) void*)l, 16, 0, 0);
}

// ------------------------------------------------- batched weight casts
// 16x [256,256]: z = l*4+which (k,v,q,o).  grid (8,8,16)
__global__ __launch_bounds__(256) void k_wt4(const float* __restrict__ wk,
    const float* __restrict__ wv, const float* __restrict__ wq,
    const float* __restrict__ wo, ushort* __restrict__ Wt)
{
    const int z = blockIdx.z, l = z >> 2, wh = z & 3;
    const float* src = (wh == 0) ? wk : (wh == 1) ? wv : (wh == 2) ? wq : wo;
    src += (size_t)l * 65536;
    ushort* d = Wt + (size_t)l * 786432 + (size_t)wh * 65536;
    __shared__ float tl[32][33];
    const int n0 = blockIdx.x * 32, k0 = blockIdx.y * 32;
    const int tx = threadIdx.x & 31, ty = threadIdx.x >> 5;
#pragma unroll
    for (int i = 0; i < 4; i++)
        tl[ty + i*8][tx] = src[(size_t)(k0 + ty + i*8) * 256 + n0 + tx];
    __syncthreads();
#pragma unroll
    for (int i = 0; i < 4; i++)
        d[(size_t)(n0 + ty + i*8) * 256 + k0 + tx] = f2bf(tl[tx][ty + i*8]);
}

// 6x [256,1024] -> [1024,256]: ff1 x4, proj_w1, head_w1.  grid (32,8,6)
__global__ __launch_bounds__(256) void k_wtA(const float* __restrict__ ff1,
    const float* __restrict__ pw1, const float* __restrict__ hw1,
    ushort* __restrict__ Wt)
{
    const int z = blockIdx.z;
    const float* src; ushort* d;
    if (z < 4)      { src = ff1 + (size_t)z*262144; d = Wt + (size_t)z*786432 + 262144; }
    else if (z == 4){ src = pw1; d = Wt + (size_t)4*786432; }
    else            { src = hw1; d = Wt + (size_t)4*786432 + 524288; }
    __shared__ float tl[32][33];
    const int n0 = blockIdx.x * 32, k0 = blockIdx.y * 32;
    const int tx = threadIdx.x & 31, ty = threadIdx.x >> 5;
#pragma unroll
    for (int i = 0; i < 4; i++)
        tl[ty + i*8][tx] = src[(size_t)(k0 + ty + i*8) * 1024 + n0 + tx];
    __syncthreads();
#pragma unroll
    for (int i = 0; i < 4; i++)
        d[(size_t)(n0 + ty + i*8) * 256 + k0 + tx] = f2bf(tl[tx][ty + i*8]);
}

// 5x [1024,256] -> [256,1024]: ff2 x4, proj_w2.  grid (8,32,5)
__global__ __launch_bounds__(256) void k_wtB(const float* __restrict__ ff2,
    const float* __restrict__ pw2, ushort* __restrict__ Wt)
{
    const int z = blockIdx.z;
    const float* src; ushort* d;
    if (z < 4) { src = ff2 + (size_t)z*262144; d = Wt + (size_t)z*786432 + 524288; }
    else       { src = pw2; d = Wt + (size_t)4*786432 + 262144; }
    __shared__ float tl[32][33];
    const int n0 = blockIdx.x * 32, k0 = blockIdx.y * 32;
    const int tx = threadIdx.x & 31, ty = threadIdx.x >> 5;
#pragma unroll
    for (int i = 0; i < 4; i++)
        tl[ty + i*8][tx] = src[(size_t)(k0 + ty + i*8) * 256 + n0 + tx];
    __syncthreads();
#pragma unroll
    for (int i = 0; i < 4; i++)
        d[(size_t)(n0 + ty + i*8) * 1024 + k0 + tx] = f2bf(tl[tx][ty + i*8]);
}

__global__ __launch_bounds__(256) void k_pcast(const float* __restrict__ src,
    ushort* __restrict__ dst, int n)
{
    int i = blockIdx.x*256 + threadIdx.x;
    if (i < n) dst[i] = f2bf(src[i]);
}

// ------------------------------------------------- bf16 MFMA GEMM 128x128
template<int CBF>
__global__ __launch_bounds__(256) void gemm_bf(
    const ushort* __restrict__ A, const ushort* __restrict__ Bt,
    const float* __restrict__ bias, const float* __restrict__ res,
    void* __restrict__ Cv, int Mrows, int N, int K, int act, int addC)
{
    __shared__ ushort As[8192];
    __shared__ ushort Bs[8192];
    const int t = threadIdx.x;
    const int l = t & 63, wid = t >> 6;
    const int row0 = blockIdx.y * 128, col0 = blockIdx.x * 128;
    const int lr = l & 15, q = l >> 4;

    const int ar0 = min(row0 + wid*32      + lr, Mrows - 1);
    const int ar1 = min(row0 + wid*32 + 16 + lr, Mrows - 1);
    const int br0 = col0 + wid*32      + lr;
    const int br1 = col0 + wid*32 + 16 + lr;
    const ushort* gA0 = A  + (size_t)ar0 * K + q*8;
    const ushort* gA1 = A  + (size_t)ar1 * K + q*8;
    const ushort* gB0 = Bt + (size_t)br0 * K + q*8;
    const ushort* gB1 = Bt + (size_t)br1 * K + q*8;
    ushort* lA0 = As + wid*1024;
    ushort* lA1 = As + wid*1024 + 512;
    ushort* lB0 = Bs + wid*1024;
    ushort* lB1 = Bs + wid*1024 + 512;

    const int rgA = (wid & 1) * 4;
    const int rgB = (wid >> 1) * 4;

    f32x4 acc[4][4] = {};

    for (int k0 = 0; k0 < K; k0 += 32) {
        gload16(gA0 + k0, lA0);
        gload16(gA1 + k0, lA1);
        gload16(gB0 + k0, lB0);
        gload16(gB1 + k0, lB1);
        __syncthreads();
        bf16x8 af[4];
#pragma unroll
        for (int mi = 0; mi < 4; mi++)
            af[mi] = *(const bf16x8*)&As[(rgA + mi)*512 + l*8];
#pragma unroll
        for (int ni = 0; ni < 4; ni++) {
            bf16x8 bfv = *(const bf16x8*)&Bs[(rgB + ni)*512 + l*8];
#pragma unroll
            for (int mi = 0; mi < 4; mi++)
                acc[mi][ni] = __builtin_amdgcn_mfma_f32_16x16x32_bf16(
                    af[mi], bfv, acc[mi][ni], 0, 0, 0);
        }
        __syncthreads();
    }

#pragma unroll
    for (int mi = 0; mi < 4; mi++) {
#pragma unroll
        for (int j = 0; j < 4; j++) {
            int row = row0 + (wid & 1)*64 + mi*16 + q*4 + j;
            if (row >= Mrows) continue;
#pragma unroll
            for (int ni = 0; ni < 4; ni++) {
                int col = col0 + (wid >> 1)*64 + ni*16 + lr;
                float v = acc[mi][ni][j];
                if (bias) v += bias[col];
                if (act == 1) v = fmaxf(v, 0.f);
                else if (act == 2) v = geluf(v);
                size_t ci = (size_t)row * N + col;
                if (res) v += res[ci];
                if (CBF) {
                    ((ushort*)Cv)[ci] = f2bf(v);
                } else {
                    float* C = (float*)Cv;
                    if (addC) v += C[ci];
                    C[ci] = v;
                }
            }
        }
    }
}

// ------------------------------------------------- small kernels
__global__ __launch_bounds__(256) void k_zero(float* __restrict__ p, int n) {
    int i = blockIdx.x*256 + threadIdx.x;
    if (i < n) p[i] = 0.f;
}

__global__ __launch_bounds__(256) void k_se1(const float* __restrict__ x,
    const float* __restrict__ w1, float* __restrict__ t1)
{
    const int blk = blockIdx.x, b = blockIdx.y, t = threadIdx.x;
    const int k0 = blk * 250;
    float acc = 0.f;
    for (int kk = 0; kk < 250; kk++) {
        float xv = x[b*Gg + k0 + kk];
        acc += xv * w1[(size_t)(k0 + kk)*256 + t];
    }
    atomicAdd(&t1[b*256 + t], acc);
}

__global__ __launch_bounds__(256) void k_se2(const float* __restrict__ t1,
    const float* __restrict__ b1, const float* __restrict__ w2,
    const float* __restrict__ b2, float* __restrict__ samp)
{
    const int b = blockIdx.x, t = threadIdx.x;
    __shared__ float s1[256];
    s1[t] = fmaxf(t1[b*256 + t] + b1[t], 0.f);
    __syncthreads();
    float acc = 0.f;
    for (int n = 0; n < 256; n++) acc += s1[n] * w2[(size_t)n*256 + t];
    samp[b*256 + t] = acc + b2[t];
}

// embed: one wave per row, 4 cols/lane.  grid (G/4)
__global__ __launch_bounds__(256) void k_embed(const float* __restrict__ x,
    const float* __restrict__ gene_emb, const float* __restrict__ samp,
    ushort* __restrict__ outb, int b)
{
    const int w = threadIdx.x >> 6, l = threadIdx.x & 63;
    const int g = blockIdx.x * 4 + w;
    const float xv = x[b*Gg + g];
    const int d0 = l * 4;
    float4 gev = *(const float4*)&gene_emb[(size_t)g*256 + d0];
    float4 sv  = *(const float4*)&samp[b*256 + d0];
    float gv[4] = {gev.x, gev.y, gev.z, gev.w};
    float sp[4] = {sv.x, sv.y, sv.z, sv.w};
    ushort4 o;
    ushort* op = (ushort*)&o;
#pragma unroll
    for (int i = 0; i < 4; i++) {
        int d = d0 + i, j = d & 127;
        float ang = xv * expf(-(float)j * 0.035977892078032f);   // ln(100)/128
        float ree = (d < 128) ? sinf(ang) : cosf(ang);
        if (xv == -10.0f) ree = 0.f;
        op[i] = f2bf(gv[i] + ree + sp[i]);
    }
    *(ushort4*)&outb[(size_t)g*256 + d0] = o;
}

// LayerNorm: one wave per row, float4/lane, wave-local reduce.  grid (rows/4)
__global__ __launch_bounds__(256) void k_ln(const float* __restrict__ src,
    ushort* __restrict__ dst, const float* __restrict__ gam,
    const float* __restrict__ bet)
{
    const int w = threadIdx.x >> 6, l = threadIdx.x & 63;
    const size_t row = (size_t)blockIdx.x * 4 + w;
    const float4 v = *(const float4*)&src[row*256 + l*4];
    float s1 = v.x + v.y + v.z + v.w;
    float s2 = v.x*v.x + v.y*v.y + v.z*v.z + v.w*v.w;
#pragma unroll
    for (int off = 32; off; off >>= 1) {
        s1 += __shfl_xor(s1, off);
        s2 += __shfl_xor(s2, off);
    }
    float m1 = s1 * (1.f/256.f);
    float m2 = s2 * (1.f/256.f);
    float inv = rsqrtf(m2 - m1*m1 + 1e-5f);
    const float4 g4 = *(const float4*)&gam[l*4];
    const float4 b4 = *(const float4*)&bet[l*4];
    ushort4 o;
    o.x = f2bf((v.x - m1)*inv*g4.x + b4.x);
    o.y = f2bf((v.y - m1)*inv*g4.y + b4.y);
    o.z = f2bf((v.z - m1)*inv*g4.z + b4.z);
    o.w = f2bf((v.w - m1)*inv*g4.w + b4.w);
    *(ushort4*)&dst[row*256 + l*4] = o;
}

// ------------------------------------------------- MFMA FAVOR+ attention
// kmax partials + zero ksum slots.  grid (128, 8)
__global__ __launch_bounds__(256) void k_kmax(const ushort* __restrict__ qkv,
    const ushort* __restrict__ projb, float* __restrict__ kmaxp,
    float* __restrict__ ksump)
{
    const int h = blockIdx.y, blk = blockIdx.x;
    const int t = threadIdx.x;
    const int w = t >> 6, l = t & 63;
    const int lr = l & 15, lq = l >> 4;
    if (t < 128) ksump[(size_t)(h*128 + blk)*128 + t] = 0.f;
    bf16x8 pb[8];
#pragma unroll
    for (int nt = 0; nt < 8; nt++)
        pb[nt] = *(const bf16x8*)(projb + (nt*16 + lr)*32 + lq*8);
    const int g0 = blk * NBLK;
    const int rows = min(NBLK, Gg - g0);
    float mx = -1e30f;
    for (int gc = 0; gc < rows; gc += 64) {
        int row = min(g0 + gc + w*16 + lr, Gg - 1);
        bf16x8 af = *(const bf16x8*)(qkv + (size_t)row*QKVS + h*32 + lq*8);
        f32x4 z = {};
#pragma unroll
        for (int nt = 0; nt < 8; nt++) {
            f32x4 dd = __builtin_amdgcn_mfma_f32_16x16x32_bf16(af, pb[nt], z, 0, 0, 0);
            mx = fmaxf(mx, fmaxf(fmaxf(dd[0], dd[1]), fmaxf(dd[2], dd[3])));
        }
    }
#pragma unroll
    for (int off = 32; off; off >>= 1) mx = fmaxf(mx, __shfl_xor(mx, off));
    __shared__ float sm[4];
    if (l == 0) sm[w] = mx;
    __syncthreads();
    if (t == 0)
        kmaxp[h*128 + blk] = fmaxf(fmaxf(sm[0], sm[1]), fmaxf(sm[2], sm[3]));
}

// per-block ctx partial (plain stores) + ksum slot.  grid (128, 8)
__global__ __launch_bounds__(256) void k_ctx(const ushort* __restrict__ qkv,
    const ushort* __restrict__ projb, const float* __restrict__ kmaxp,
    float* __restrict__ ctxp, float* __restrict__ ksump)
{
    __shared__ ushort kpsT[128][72];   // [m][g] bf16
    __shared__ ushort vt[32][72];      // [dh][g] bf16
    __shared__ float diag[64];
    const int h = blockIdx.y, blk = blockIdx.x;
    const int t = threadIdx.x;
    const int w = t >> 6, l = t & 63;
    const int lr = l & 15, lq = l >> 4;
    bf16x8 pb[8];
#pragma unroll
    for (int nt = 0; nt < 8; nt++)
        pb[nt] = *(const bf16x8*)(projb + (nt*16 + lr)*32 + lq*8);
    float kmr = fmaxf(kmaxp[h*128 + l], kmaxp[h*128 + 64 + l]);
#pragma unroll
    for (int off = 32; off; off >>= 1) kmr = fmaxf(kmr, __shfl_xor(kmr, off));
    const float km = kmr * DN;
    const int g0 = blk * NBLK;
    const int rows = min(NBLK, Gg - g0);
    f32x4 cacc[2][2] = {};
    float ksacc[8] = {};
    for (int gc = 0; gc < rows; gc += 64) {
        const int nr = min(64, rows - gc);
        const int rbase = g0 + gc;
        int arow = min(rbase + w*16 + lr, Gg - 1);
        bf16x8 af = *(const bf16x8*)(qkv + (size_t)arow*QKVS + h*32 + lq*8);
        float s = 0.f;
#pragma unroll
        for (int j = 0; j < 8; j++) { float kv = bf2f((ushort)af[j]); s += kv*kv; }
        s += __shfl_xor(s, 16); s += __shfl_xor(s, 32);
        if (l < 16) diag[w*16 + l] = DN2H * s;
        f32x4 z = {};
        f32x4 dd[8];
#pragma unroll
        for (int nt = 0; nt < 8; nt++)
            dd[nt] = __builtin_amdgcn_mfma_f32_16x16x32_bf16(af, pb[nt], z, 0, 0, 0);
        __syncthreads();   // diag ready; prev-chunk LDS reads done
        float dg[4];
#pragma unroll
        for (int j = 0; j < 4; j++) dg[j] = diag[w*16 + lq*4 + j];
#pragma unroll
        for (int nt = 0; nt < 8; nt++) {
#pragma unroll
            for (int j = 0; j < 4; j++) {
                int rj = w*16 + lq*4 + j;
                float kp = 0.f;
                if (rj < nr) kp = RATIO * (expf(DN*dd[nt][j] - dg[j] - km) + EPSK);
                ksacc[nt] += kp;
                kpsT[nt*16 + lr][rj] = f2bf(kp);
            }
        }
        for (int i = t; i < 512; i += 256) {
            int r = i >> 3, c4 = (i & 7) * 4;
            int vrow = min(rbase + r, Gg - 1);
            const ushort* vp = qkv + (size_t)vrow*QKVS + 256 + h*32 + c4;
            vt[c4+0][r] = vp[0]; vt[c4+1][r] = vp[1];
            vt[c4+2][r] = vp[2]; vt[c4+3][r] = vp[3];
        }
        __syncthreads();   // kpsT + vt ready
#pragma unroll
        for (int ks = 0; ks < 2; ks++) {
            bf16x8 a0 = *(const bf16x8*)&vt[lr][ks*32 + lq*8];
            bf16x8 a1 = *(const bf16x8*)&vt[16 + lr][ks*32 + lq*8];
#pragma unroll
            for (int ntp = 0; ntp < 2; ntp++) {
                bf16x8 bfr = *(const bf16x8*)&kpsT[(w*2 + ntp)*16 + lr][ks*32 + lq*8];
                cacc[0][ntp] = __builtin_amdgcn_mfma_f32_16x16x32_bf16(a0, bfr, cacc[0][ntp], 0, 0, 0);
                cacc[1][ntp] = __builtin_amdgcn_mfma_f32_16x16x32_bf16(a1, bfr, cacc[1][ntp], 0, 0, 0);
            }
        }
    }
    // private slot: plain stores, thread-unique addresses (full 4096 coverage)
    float* cslot = ctxp + (size_t)(h*128 + blk)*4096;
#pragma unroll
    for (int dt = 0; dt < 2; dt++)
#pragma unroll
        for (int ntp = 0; ntp < 2; ntp++)
#pragma unroll
            for (int j = 0; j < 4; j++)
                cslot[(dt*16 + lq*4 + j)*128 + (w*2 + ntp)*16 + lr] = cacc[dt][ntp][j];
    float* kslot = ksump + (size_t)(h*128 + blk)*128;
#pragma unroll
    for (int nt = 0; nt < 8; nt++) {
        float v = ksacc[nt];
        v += __shfl_down(v, 32);
        v += __shfl_down(v, 16);
        if (l < 16) atomicAdd(&kslot[nt*16 + l], v);   // 4-way (one per wave)
    }
}

// reduce 128 slots -> final ctxT/ksum.  grid (16, 8)
__global__ __launch_bounds__(256) void k_cred(const float* __restrict__ ctxp,
    const float* __restrict__ ksump, float* __restrict__ ctxT,
    float* __restrict__ ksum)
{
    const int h = blockIdx.y, blk = blockIdx.x;
    const int i = blk*256 + threadIdx.x;   // 0..4095
    float s = 0.f;
    for (int sl = 0; sl < 128; sl++)
        s += ctxp[(size_t)(h*128 + sl)*4096 + i];
    ctxT[(size_t)h*4096 + i] = s;
    if (blk == 0 && threadIdx.x < 128) {
        float ks = 0.f;
        for (int sl = 0; sl < 128; sl++)
            ks += ksump[(size_t)(h*128 + sl)*128 + threadIdx.x];
        ksum[h*128 + threadIdx.x] = ks;
    }
}

// o = dinv * (qp @ ctx).  grid (128, 8)
__global__ __launch_bounds__(256) void k_attn(const ushort* __restrict__ qkv,
    const ushort* __restrict__ projb, const float* __restrict__ ctxT,
    const float* __restrict__ ksum, ushort* __restrict__ obuf)
{
    __shared__ ushort qps[64][136];
    __shared__ ushort ctxb[32][136];
    __shared__ float ksl[128];
    __shared__ float dgq[64];
    const int h = blockIdx.y, blk = blockIdx.x;
    const int t = threadIdx.x;
    const int w = t >> 6, l = t & 63;
    const int lr = l & 15, lq = l >> 4;
    bf16x8 pb[8];
#pragma unroll
    for (int nt = 0; nt < 8; nt++)
        pb[nt] = *(const bf16x8*)(projb + (nt*16 + lr)*32 + lq*8);
    for (int i = t; i < 4096; i += 256)
        ctxb[i >> 7][i & 127] = f2bf(ctxT[(size_t)h*4096 + i]);
    if (t < 128) ksl[t] = ksum[h*128 + t];
    __syncthreads();
    bf16x8 cb[2][4];
#pragma unroll
    for (int dt = 0; dt < 2; dt++)
#pragma unroll
        for (int ks = 0; ks < 4; ks++)
            cb[dt][ks] = *(const bf16x8*)&ctxb[dt*16 + lr][ks*32 + lq*8];
    const int g0 = blk * NBLK;
    const int rows = min(NBLK, Gg - g0);
    for (int gc = 0; gc < rows; gc += 64) {
        const int nr = min(64, rows - gc);
        const int rbase = g0 + gc;
        int arow = min(rbase + w*16 + lr, Gg - 1);
        bf16x8 af = *(const bf16x8*)(qkv + (size_t)arow*QKVS + 512 + h*32 + lq*8);
        float s = 0.f;
#pragma unroll
        for (int j = 0; j < 8; j++) { float qv = bf2f((ushort)af[j]); s += qv*qv; }
        s += __shfl_xor(s, 16); s += __shfl_xor(s, 32);
        if (l < 16) dgq[w*16 + l] = DN2H * s;
        f32x4 z = {};
        f32x4 dd[8];
#pragma unroll
        for (int nt = 0; nt < 8; nt++)
            dd[nt] = __builtin_amdgcn_mfma_f32_16x16x32_bf16(af, pb[nt], z, 0, 0, 0);
        __syncthreads();
        float dg[4], mq[4], den[4], dinv[4];
#pragma unroll
        for (int j = 0; j < 4; j++) {
            dg[j] = dgq[w*16 + lq*4 + j];
            float m = -1e30f;
#pragma unroll
            for (int nt = 0; nt < 8; nt++) m = fmaxf(m, dd[nt][j]);
            mq[j] = m;
        }
#pragma unroll
        for (int off = 1; off < 16; off <<= 1)
#pragma unroll
            for (int j = 0; j < 4; j++) mq[j] = fmaxf(mq[j], __shfl_xor(mq[j], off));
#pragma unroll
        for (int j = 0; j < 4; j++) { mq[j] = DN*mq[j]; den[j] = 0.f; }
#pragma unroll
        for (int nt = 0; nt < 8; nt++) {
            float kv = ksl[nt*16 + lr];
#pragma unroll
            for (int j = 0; j < 4; j++) {
                float p = RATIO * (expf(DN*dd[nt][j] - dg[j] - mq[j]) + EPSK);
                dd[nt][j] = p;
                den[j] += p * kv;
            }
        }
#pragma unroll
        for (int off = 1; off < 16; off <<= 1)
#pragma unroll
            for (int j = 0; j < 4; j++) den[j] += __shfl_xor(den[j], off);
#pragma unroll
        for (int j = 0; j < 4; j++) dinv[j] = 1.f / den[j];
#pragma unroll
        for (int nt = 0; nt < 8; nt++)
#pragma unroll
            for (int j = 0; j < 4; j++)
                qps[w*16 + lq*4 + j][nt*16 + lr] = f2bf(dd[nt][j]);
        __syncthreads();
        f32x4 oacc[2] = {};
#pragma unroll
        for (int ks = 0; ks < 4; ks++) {
            bf16x8 aq = *(const bf16x8*)&qps[w*16 + lr][ks*32 + lq*8];
            oacc[0] = __builtin_amdgcn_mfma_f32_16x16x32_bf16(aq, cb[0][ks], oacc[0], 0, 0, 0);
            oacc[1] = __builtin_amdgcn_mfma_f32_16x16x32_bf16(aq, cb[1][ks], oacc[1], 0, 0, 0);
        }
#pragma unroll
        for (int dt = 0; dt < 2; dt++)
#pragma unroll
            for (int j = 0; j < 4; j++) {
                int rj = w*16 + lq*4 + j;
                if (rj < nr)
                    obuf[(size_t)(rbase + rj)*256 + h*32 + dt*16 + lr]
                        = f2bf(oacc[dt][j] * dinv[j]);
            }
    }
}

// head layer 2.  16 rows/block
__global__ __launch_bounds__(256) void k_head(const ushort* __restrict__ u,
    const float* __restrict__ w2, const float* __restrict__ b2,
    float* __restrict__ outp, int nrows)
{
    const int wv = threadIdx.x >> 6, l = threadIdx.x & 63;
    const int row0 = blockIdx.x * 16 + wv * 4;
#pragma unroll
    for (int it = 0; it < 4; it++) {
        int row = row0 + it;
        if (row >= nrows) break;
        float a = 0.f;
#pragma unroll
        for (int k = 0; k < 16; k++)
            a += bf2f(u[(size_t)row*1024 + l + k*64]) * w2[l + k*64];
        for (int off = 32; off; off >>= 1) a += __shfl_down(a, off);
        if (l == 0) outp[row] = fmaxf(a + b2[0], 0.f);
    }
}

// ---------------------------------------------------------------- launch
extern "C" void kernel_launch(void* const* d_in, const int* in_sizes, int n_in,
                              void* d_out, int out_size, void* d_ws, size_t ws_size,
                              hipStream_t stream)
{
    const float* x        = (const float*)d_in[0];
    const float* gene_emb = (const float*)d_in[1];
    const float* se_w1    = (const float*)d_in[2];
    const float* se_b1    = (const float*)d_in[3];
    const float* se_w2    = (const float*)d_in[4];
    const float* se_b2    = (const float*)d_in[5];
    const float* proj_w1  = (const float*)d_in[6];
    const float* proj_b1  = (const float*)d_in[7];
    const float* proj_w2  = (const float*)d_in[8];
    const float* proj_b2  = (const float*)d_in[9];
    const float* ln1_g    = (const float*)d_in[10];
    const float* ln1_b    = (const float*)d_in[11];
    const float* wq       = (const float*)d_in[12];
    const float* wk       = (const float*)d_in[13];
    const float* wv       = (const float*)d_in[14];
    const float* wo       = (const float*)d_in[15];
    const float* bo       = (const float*)d_in[16];
    const float* ln2_g    = (const float*)d_in[17];
    const float* ln2_b    = (const float*)d_in[18];
    const float* ff_w1    = (const float*)d_in[19];
    const float* ff_b1    = (const float*)d_in[20];
    const float* ff_w2    = (const float*)d_in[21];
    const float* ff_b2    = (const float*)d_in[22];
    const float* featp    = (const float*)d_in[23];
    const float* norm_g   = (const float*)d_in[24];
    const float* norm_b   = (const float*)d_in[25];
    const float* head_w1  = (const float*)d_in[26];
    const float* head_b1  = (const float*)d_in[27];
    const float* head_w2  = (const float*)d_in[28];
    const float* head_b2  = (const float*)d_in[29];
    float* out = (float*)d_out;

    const int CHKF = (ws_size >= (size_t)102000000) ? 20000 : 10000;
    const int NCHF = Gg / CHKF;

    float* w = (float*)d_ws;
    const size_t SB = (size_t)Gg * Dd;
    float* f_h = w;                              // [G,D] fp32
    float* B1  = w + SB;                         // [G,D] fp32 (y); ctx slots during attn
    float* t1    = w + 2*SB;                     // 2048
    float* samp  = t1 + 2048;                    // 2048
    float* ctx   = samp + 2048;                  // 32768 (final ctx^T [h][dh][m])
    float* ksum  = ctx + 32768;                  // 1024
    float* kmaxp = ksum + 1024;                  // 1024
    ushort* Ab  = (ushort*)(w + 2*SB + 40000);   // [G,256] bf16
    ushort* U   = Ab + SB;                       // QKV [G,768] | B4 [CHKF,1024]
    const size_t usz = (size_t)Gg * QKVS > (size_t)CHKF * FFf
                     ? (size_t)Gg * QKVS : (size_t)CHKF * FFf;
    ushort* Wt  = U + usz;                       // 3,932,160 bf16
    ushort* projb = Wt + 3932160;                // 16384 bf16
    ushort* QKVb = U;
    ushort* B4   = U;
    // attention slot buffers alias B1 (dead between ff2 and wo-gemm)
    float* ctxp  = B1;                           // 1024 slots x 4096 = 4,194,304
    float* ksump = B1 + 4194304;                 // 1024 x 128 = 131,072

    auto gemm = [&](int CBF, const ushort* A, const ushort* Bw,
                    const float* bias, const float* res, void* C,
                    int Mr, int N, int K, int act, int addC) {
        dim3 grid(N/128, (Mr + 127)/128);
        if (CBF) gemm_bf<1><<<grid, 256, 0, stream>>>(A, Bw, bias, res, C, Mr, N, K, act, addC);
        else     gemm_bf<0><<<grid, 256, 0, stream>>>(A, Bw, bias, res, C, Mr, N, K, act, addC);
    };

    // ---------------- weight casts (3 batched launches)
    k_wt4<<<dim3(8, 8, 16), 256, 0, stream>>>(wk, wv, wq, wo, Wt);
    k_wtA<<<dim3(32, 8, 6), 256, 0, stream>>>(ff_w1, proj_w1, head_w1, Wt);
    k_wtB<<<dim3(8, 32, 5), 256, 0, stream>>>(ff_w2, proj_w2, Wt);
    k_pcast<<<64, 256, 0, stream>>>(featp, projb, Ll*Mm*DHh);
    const size_t LW = 786432;
    ushort* pj1T = Wt + 4*LW;
    ushort* pj2T = pj1T + 262144;
    ushort* hd1T = pj2T + 262144;

    // ---------------- sample embedding (all batches)
    k_zero<<<8, 256, 0, stream>>>(t1, 2048);
    k_se1<<<dim3(80, 8), 256, 0, stream>>>(x, se_w1, t1);
    k_se2<<<8, 256, 0, stream>>>(t1, se_b1, se_w2, se_b2, samp);

    // ---------------- per batch full network
    for (int b = 0; b < Bb; b++) {
        k_embed<<<Gg/4, 256, 0, stream>>>(x, gene_emb, samp, Ab, b);
        for (int c = 0; c < NCHF; c++) {
            size_t off = (size_t)c * CHKF * Dd;
            gemm(1, Ab + off, pj1T, proj_b1, nullptr, B4, CHKF, FFf, Dd, 1, 0);
            gemm(0, B4, pj2T, proj_b2, nullptr, f_h + off, CHKF, Dd, FFf, 0, 0);
        }
        for (int l = 0; l < Ll; l++) {
            ushort* lw = Wt + (size_t)l * LW;
            const ushort* qkvT = lw;
            const ushort* oT   = lw + 196608;
            const ushort* f1T  = lw + 262144;
            const ushort* f2T  = lw + 524288;
            const ushort* pjb  = projb + (size_t)l*Mm*DHh;

            k_ln<<<Gg/4, 256, 0, stream>>>(f_h, Ab, ln1_g + l*Dd, ln1_b + l*Dd);
            gemm(1, Ab, qkvT, nullptr, nullptr, QKVb, Gg, QKVS, Dd, 0, 0);
            k_kmax<<<dim3(128, 8), 256, 0, stream>>>(QKVb, pjb, kmaxp, ksump);
            k_ctx<<<dim3(128, 8), 256, 0, stream>>>(QKVb, pjb, kmaxp, ctxp, ksump);
            k_cred<<<dim3(16, 8), 256, 0, stream>>>(ctxp, ksump, ctx, ksum);
            k_attn<<<dim3(128, 8), 256, 0, stream>>>(QKVb, pjb, ctx, ksum, Ab);
            gemm(0, Ab, oT, bo + l*Dd, f_h, B1, Gg, Dd, Dd, 0, 0);        // y fp32
            k_ln<<<Gg/4, 256, 0, stream>>>(B1, Ab, ln2_g + l*Dd, ln2_b + l*Dd);
            for (int c = 0; c < NCHF; c++) {
                size_t off = (size_t)c * CHKF * Dd;
                gemm(1, Ab + off, f1T, ff_b1 + l*FFf, nullptr, B4, CHKF, FFf, Dd, 2, 0);
                gemm(0, B4, f2T, ff_b2 + l*Dd, B1 + off, f_h + off, CHKF, Dd, FFf, 0, 1);
            }
        }
        k_ln<<<Gg/4, 256, 0, stream>>>(f_h, Ab, norm_g, norm_b);
        for (int c = 0; c < NCHF; c++) {
            size_t off = (size_t)c * CHKF * Dd;
            gemm(1, Ab + off, hd1T, head_b1, nullptr, B4, CHKF, FFf, Dd, 1, 0);
            k_head<<<(CHKF + 15)/16, 256, 0, stream>>>(B4, head_w2, head_b2,
                                                       out + b*Gg + c*CHKF, CHKF);
        }
    }
}